// Round 2
// baseline (243.059 us; speedup 1.0000x reference)
//
#include <hip/hip_runtime.h>
#include <stdint.h>

typedef unsigned short u16;
typedef unsigned int   u32;
typedef __attribute__((ext_vector_type(8))) short short8;
typedef __attribute__((ext_vector_type(4))) float f32x4;

#define DEV static __device__ __forceinline__

static constexpr int Bc = 2, Tc = 2048, Hc = 768, NH = 12, HD = 64;
static constexpr int BTc = Bc * Tc;      // 4096 rows
static constexpr int N3 = 3 * Hc;        // 2304
static constexpr int NBH = Bc * NH;      // 24
static constexpr float QSCALE = 0.125f * 1.44269504088896f; // 1/sqrt(64) * log2(e)

DEV u16 f2bf(float f) {
  u32 u = __float_as_uint(f);
  u32 r = (u + 0x7fffu + ((u >> 16) & 1u)) >> 16;  // RNE
  return (u16)r;
}

DEV float fexp2(float x) {
#if __has_builtin(__builtin_amdgcn_exp2f)
  return __builtin_amdgcn_exp2f(x);
#else
  return exp2f(x);
#endif
}

DEV void gl_lds16(const u16* g, u16* l) {
  __builtin_amdgcn_global_load_lds(
      (const __attribute__((address_space(1))) u32*)g,
      (__attribute__((address_space(3))) u32*)l, 16, 0, 0);
}

#define MFMA(a, b, c) __builtin_amdgcn_mfma_f32_16x16x32_bf16((a), (b), (c), 0, 0, 0)

// ---------------- cast x (fp32 -> bf16), 8 elems/thread ----------------
__global__ void k_cvt(const float4* __restrict__ in, uint4* __restrict__ out, int n8) {
  int i = blockIdx.x * 256 + threadIdx.x;
  if (i >= n8) return;
  float4 a = in[2 * i], b = in[2 * i + 1];
  uint4 o;
  o.x = f2bf(a.x) | ((u32)f2bf(a.y) << 16);
  o.y = f2bf(a.z) | ((u32)f2bf(a.w) << 16);
  o.z = f2bf(b.x) | ((u32)f2bf(b.y) << 16);
  o.w = f2bf(b.z) | ((u32)f2bf(b.w) << 16);
  out[i] = o;
}

// ------------- transpose + cast weights: in fp32 [R][C] -> out bf16 [C][R] -------------
__global__ __launch_bounds__(256) void k_transpose_w(const float* __restrict__ in,
                                                     u16* __restrict__ out, int R, int C) {
  __shared__ u16 tile[64][65];
  int c0 = blockIdx.x * 64, r0 = blockIdx.y * 64;
  int tx = threadIdx.x, ty = threadIdx.y;  // block (64,4)
  for (int i = ty; i < 64; i += 4)
    tile[i][tx] = f2bf(in[(size_t)(r0 + i) * C + c0 + tx]);
  __syncthreads();
  for (int i = ty; i < 64; i += 4)
    out[(size_t)(c0 + i) * R + r0 + tx] = tile[tx][i];
}

// ------------- transpose V per head: [bh][2048][64] -> VT [bh][64][2048] (bf16) -------------
__global__ __launch_bounds__(256) void k_transpose_v(const u16* __restrict__ V,
                                                     u16* __restrict__ VT) {
  __shared__ u16 tile[64][65];
  int bh = blockIdx.y;
  int t0 = blockIdx.x * 64;
  const u16* src = V + (size_t)bh * Tc * HD;
  u16* dst = VT + (size_t)bh * Tc * HD;
  int tx = threadIdx.x, ty = threadIdx.y;
  for (int i = ty; i < 64; i += 4)
    tile[i][tx] = src[(size_t)(t0 + i) * HD + tx];
  __syncthreads();
  for (int i = ty; i < 64; i += 4)
    dst[(size_t)i * Tc + t0 + tx] = tile[tx][i];
}

// ---------------- GEMM: C = A[M,K] * BT[N,K]^T (+bias), bf16 in, fp32 acc ----------------
// EPI=0: scatter into Qh(scaled)/Kh/Vh per-head bf16 layouts. EPI=1: fp32 out + bias.
template <int EPI>
__global__ __launch_bounds__(256) void k_gemm(const u16* __restrict__ A,
                                              const u16* __restrict__ BTm,
                                              const float* __restrict__ bias,
                                              u16* __restrict__ oQ, u16* __restrict__ oK,
                                              u16* __restrict__ oV, float* __restrict__ oF,
                                              int M, int N, int K) {
  __shared__ u16 As[128 * 32];
  __shared__ u16 Bs[128 * 32];
  const int tid = threadIdx.x;
  const int lane = tid & 63, wave = tid >> 6;
  const int wr = wave >> 1, wc = wave & 1;
  const int row0 = blockIdx.y * 128, col0 = blockIdx.x * 128;

  f32x4 acc[4][4];
#pragma unroll
  for (int m = 0; m < 4; ++m)
#pragma unroll
    for (int n = 0; n < 4; ++n) acc[m][n] = (f32x4)(0.f);

  const int srow = lane >> 2;
  const int sg = lane & 3;
  const int sf = (lane >> 3) & 3;
  const int kfetch = ((sg ^ sf) * 8);

  const int r16 = lane & 15;
  const int g = lane >> 4;
  const int fr = (r16 >> 1) & 3;
  const int koff = ((g ^ fr) * 8);

  for (int k0 = 0; k0 < K; k0 += 32) {
    if (k0) __syncthreads();
#pragma unroll
    for (int p = 0; p < 2; ++p) {
      int seg = wave * 2 + p;
      int row = seg * 16 + srow;
      gl_lds16(A + (size_t)(row0 + row) * K + k0 + kfetch, &As[seg * 512 + lane * 8]);
      gl_lds16(BTm + (size_t)(col0 + row) * K + k0 + kfetch, &Bs[seg * 512 + lane * 8]);
    }
    __syncthreads();
    short8 af[4], bf[4];
#pragma unroll
    for (int m = 0; m < 4; ++m)
      af[m] = *(const short8*)&As[(wr * 64 + m * 16 + r16) * 32 + koff];
#pragma unroll
    for (int n = 0; n < 4; ++n)
      bf[n] = *(const short8*)&Bs[(wc * 64 + n * 16 + r16) * 32 + koff];
#pragma unroll
    for (int m = 0; m < 4; ++m)
#pragma unroll
      for (int n = 0; n < 4; ++n)
        acc[m][n] = MFMA(af[m], bf[n], acc[m][n]);
  }

#pragma unroll
  for (int m = 0; m < 4; ++m) {
    int rowg = row0 + wr * 64 + m * 16 + g * 4;
#pragma unroll
    for (int n = 0; n < 4; ++n) {
      int colg = col0 + wc * 64 + n * 16 + r16;
      float bv = bias[colg];
      if constexpr (EPI == 0) {
        int which = colg / Hc;
        int hc = colg - which * Hc;
        int h = hc >> 6, d = hc & 63;
#pragma unroll
        for (int r = 0; r < 4; ++r) {
          int mg = rowg + r;
          int b = mg >> 11, t = mg & 2047;
          float v = acc[m][n][r] + bv;
          size_t dst = ((size_t)(b * NH + h) * Tc + t) * HD + d;
          if (which == 0)      oQ[dst] = f2bf(v * QSCALE);
          else if (which == 1) oK[dst] = f2bf(v);
          else                 oV[dst] = f2bf(v);
        }
      } else {
#pragma unroll
        for (int r = 0; r < 4; ++r) {
          int mg = rowg + r;
          oF[(size_t)mg * Hc + colg] = acc[m][n][r] + bv;
        }
      }
    }
  }
}

// ---------------- flash attention: 1 wave per 32 q-rows, fully independent ----------------
// Grid: 1536 blocks x 64 threads. bh = gid % 24 (fast), j = gid / 24 (slow) -> breaks
// the stride-256 CU resonance (a CU's waves get j values ~10.7 apart -> balanced).
// K/V fragments read directly from global (L2-resident, 256KB/head). No barriers.
__global__ __launch_bounds__(64) void k_attn(const u16* __restrict__ Qh,
                                             const u16* __restrict__ Kh,
                                             const u16* __restrict__ VT,
                                             const int* __restrict__ mask,
                                             u16* __restrict__ O) {
  __shared__ u16 Ps[32 * 64];  // 4KB per-wave P bounce (swizzled)
  const int gid = blockIdx.x;
  const int bh = gid % NBH;
  const int j = gid / NBH;        // 0..63, q-rows [32j, 32j+32)
  const int b = bh / NH, h = bh - b * NH;
  const int q0 = j * 32;
  const int lane = threadIdx.x;
  const int r16 = lane & 15, g = lane >> 4;

  // Q fragments for two 16-row groups (scale folded in at GEMM1 epilogue)
  short8 qf[2][2];
#pragma unroll
  for (int u = 0; u < 2; ++u) {
    const u16* qbase = Qh + ((size_t)bh * Tc + q0 + u * 16 + r16) * HD;
    qf[u][0] = *(const short8*)(qbase + g * 8);
    qf[u][1] = *(const short8*)(qbase + 32 + g * 8);
  }

  f32x4 acc[2][4];
  float mrun[2][4], lrun[2][4];
#pragma unroll
  for (int u = 0; u < 2; ++u) {
#pragma unroll
    for (int n = 0; n < 4; ++n) acc[u][n] = (f32x4)(0.f);
#pragma unroll
    for (int r = 0; r < 4; ++r) { mrun[u][r] = -3.0e38f; lrun[u][r] = 0.f; }
  }

  const int ntiles = j / 2 + 1;
  const int* mrow = mask + b * Tc;

  for (int t = 0; t < ntiles; ++t) {
    const int kb = t * 64;

    // ---- S = Q K^T (K frags direct from global; shared across both row groups) ----
    f32x4 s[2][4];
#pragma unroll
    for (int n = 0; n < 4; ++n) {
      const u16* kbase = Kh + ((size_t)bh * Tc + kb + n * 16 + r16) * HD;
      short8 kf0 = *(const short8*)(kbase + g * 8);
      short8 kf1 = *(const short8*)(kbase + 32 + g * 8);
#pragma unroll
      for (int u = 0; u < 2; ++u) {
        f32x4 z = (f32x4)(0.f);
        z = MFMA(qf[u][0], kf0, z);
        z = MFMA(qf[u][1], kf1, z);
        s[u][n] = z;
      }
    }

    // ---- key mask (+ causal on last tile) ----
    const bool diag = (t == ntiles - 1);
#pragma unroll
    for (int n = 0; n < 4; ++n) {
      int keyg = kb + n * 16 + r16;
      int km = mrow[keyg];
#pragma unroll
      for (int u = 0; u < 2; ++u)
#pragma unroll
        for (int r = 0; r < 4; ++r) {
          bool ok = (km != 0);
          if (diag) ok = ok && (keyg <= q0 + u * 16 + g * 4 + r);
          if (!ok) s[u][n][r] = -3.0e38f;
        }
    }

    // ---- online softmax (base-2 domain), per row group ----
#pragma unroll
    for (int u = 0; u < 2; ++u) {
      float alpha[4];
#pragma unroll
      for (int r = 0; r < 4; ++r) {
        float v = fmaxf(fmaxf(s[u][0][r], s[u][1][r]), fmaxf(s[u][2][r], s[u][3][r]));
        v = fmaxf(v, __shfl_xor(v, 1));
        v = fmaxf(v, __shfl_xor(v, 2));
        v = fmaxf(v, __shfl_xor(v, 4));
        v = fmaxf(v, __shfl_xor(v, 8));
        float nm = fmaxf(mrun[u][r], v);
        alpha[r] = fexp2(mrun[u][r] - nm);
        mrun[u][r] = nm;
      }
      float rs[4] = {0.f, 0.f, 0.f, 0.f};
#pragma unroll
      for (int n = 0; n < 4; ++n)
#pragma unroll
        for (int r = 0; r < 4; ++r) {
          float p = fexp2(s[u][n][r] - mrun[u][r]);
          s[u][n][r] = p;
          rs[r] += p;
        }
#pragma unroll
      for (int r = 0; r < 4; ++r) {
        float v = rs[r];
        v += __shfl_xor(v, 1);
        v += __shfl_xor(v, 2);
        v += __shfl_xor(v, 4);
        v += __shfl_xor(v, 8);
        lrun[u][r] = lrun[u][r] * alpha[r] + v;
        acc[u][0][r] *= alpha[r];
        acc[u][1][r] *= alpha[r];
        acc[u][2][r] *= alpha[r];
        acc[u][3][r] *= alpha[r];
      }
    }

    // ---- P (bf16) -> per-wave swizzled LDS, read back as A-frags (no barrier: 1 wave) ----
#pragma unroll
    for (int u = 0; u < 2; ++u)
#pragma unroll
      for (int n = 0; n < 4; ++n) {
        int key = n * 16 + r16;
        int gk = key >> 3;
#pragma unroll
        for (int r = 0; r < 4; ++r) {
          int q = u * 16 + g * 4 + r;
          Ps[q * 64 + ((gk ^ (q & 7)) * 8) + (key & 7)] = f2bf(s[u][n][r]);
        }
      }
    short8 pa[2][2];
#pragma unroll
    for (int u = 0; u < 2; ++u) {
      int row = u * 16 + r16;
      int q7 = row & 7;
      pa[u][0] = *(const short8*)&Ps[row * 64 + ((g ^ q7) * 8)];
      pa[u][1] = *(const short8*)&Ps[row * 64 + (((4 + g) ^ q7) * 8)];
    }

    // ---- O += P V (V^T frags direct from global; shared across row groups) ----
#pragma unroll
    for (int n = 0; n < 4; ++n) {
      int d = n * 16 + r16;
      const u16* vbase = VT + ((size_t)bh * HD + d) * Tc + kb;
      short8 vf0 = *(const short8*)(vbase + g * 8);
      short8 vf1 = *(const short8*)(vbase + 32 + g * 8);
#pragma unroll
      for (int u = 0; u < 2; ++u) {
        acc[u][n] = MFMA(pa[u][0], vf0, acc[u][n]);
        acc[u][n] = MFMA(pa[u][1], vf1, acc[u][n]);
      }
    }
  }

  // ---- normalize + write O[b][t][h*64+d] (bf16) ----
#pragma unroll
  for (int u = 0; u < 2; ++u)
#pragma unroll
    for (int r = 0; r < 4; ++r) {
      int qg = q0 + u * 16 + g * 4 + r;
      float inv = 1.0f / lrun[u][r];
      u16* orow = O + ((size_t)(b * Tc + qg)) * Hc + h * 64;
#pragma unroll
      for (int n = 0; n < 4; ++n) orow[n * 16 + r16] = f2bf(acc[u][n][r] * inv);
    }
}

// ---------------- launch ----------------
extern "C" void kernel_launch(void* const* d_in, const int* in_sizes, int n_in,
                              void* d_out, int out_size, void* d_ws, size_t ws_size,
                              hipStream_t stream) {
  const float* x = (const float*)d_in[0];
  const int* mask = (const int*)d_in[1];
  const float* Wqkv = (const float*)d_in[2];
  const float* bqkv = (const float*)d_in[3];
  const float* Wproj = (const float*)d_in[4];
  const float* bproj = (const float*)d_in[5];
  float* out = (float*)d_out;

  char* ws = (char*)d_ws;
  size_t off = 0;
  auto alloc = [&](size_t bytes) {
    char* p = ws + off;
    off += (bytes + 255) & ~(size_t)255;
    return p;
  };
  u16* xb     = (u16*)alloc((size_t)BTc * Hc * 2);
  u16* WqkvT  = (u16*)alloc((size_t)N3 * Hc * 2);
  u16* WprojT = (u16*)alloc((size_t)Hc * Hc * 2);
  u16* Qh     = (u16*)alloc((size_t)BTc * Hc * 2);
  u16* Kh     = (u16*)alloc((size_t)BTc * Hc * 2);
  u16* Vh     = (u16*)alloc((size_t)BTc * Hc * 2);
  u16* VT     = (u16*)alloc((size_t)BTc * Hc * 2);
  u16* Ob     = xb;  // alias: xb dead after GEMM1, reused for attention output

  int n8 = BTc * Hc / 8;
  k_cvt<<<(n8 + 255) / 256, 256, 0, stream>>>((const float4*)x, (uint4*)xb, n8);
  k_transpose_w<<<dim3(N3 / 64, Hc / 64), dim3(64, 4), 0, stream>>>(Wqkv, WqkvT, Hc, N3);
  k_transpose_w<<<dim3(Hc / 64, Hc / 64), dim3(64, 4), 0, stream>>>(Wproj, WprojT, Hc, Hc);
  k_gemm<0><<<dim3(N3 / 128, BTc / 128), 256, 0, stream>>>(xb, WqkvT, bqkv, Qh, Kh, Vh,
                                                           nullptr, BTc, N3, Hc);
  k_transpose_v<<<dim3(Tc / 64, Bc * NH), dim3(64, 4), 0, stream>>>(Vh, VT);
  k_attn<<<dim3(64 * NBH), 64, 0, stream>>>(Qh, Kh, VT, mask, Ob);
  k_gemm<1><<<dim3(Hc / 128, BTc / 128), 256, 0, stream>>>(Ob, WprojT, bproj, nullptr,
                                                           nullptr, nullptr, out, BTc, Hc, Hc);
}

// Round 3
// 142.853 us; speedup vs baseline: 1.7015x; 1.7015x over previous
//
#include <hip/hip_runtime.h>
#include <stdint.h>

typedef unsigned short u16;
typedef unsigned int   u32;
typedef unsigned char  u8;
typedef __attribute__((ext_vector_type(8))) short short8;
typedef __attribute__((ext_vector_type(4))) float f32x4;

#define DEV static __device__ __forceinline__

static constexpr int Bc = 2, Tc = 2048, Hc = 768, NH = 12, HD = 64;
static constexpr int BTc = Bc * Tc;      // 4096 rows
static constexpr int N3 = 3 * Hc;        // 2304
static constexpr int NBH = Bc * NH;      // 24
static constexpr int NITEMS = 32 * NBH;  // 768 work items (64-row q strips)
static constexpr float QSCALE = 0.125f * 1.44269504088896f; // 1/sqrt(64) * log2(e)

DEV u16 f2bf(float f) {
  u32 u = __float_as_uint(f);
  u32 r = (u + 0x7fffu + ((u >> 16) & 1u)) >> 16;  // RNE
  return (u16)r;
}

DEV float fexp2(float x) {
#if __has_builtin(__builtin_amdgcn_exp2f)
  return __builtin_amdgcn_exp2f(x);
#else
  return exp2f(x);
#endif
}

DEV void gl_lds16(const u16* g, u16* l) {
  __builtin_amdgcn_global_load_lds(
      (const __attribute__((address_space(1))) u32*)g,
      (__attribute__((address_space(3))) u32*)l, 16, 0, 0);
}

#define MFMA(a, b, c) __builtin_amdgcn_mfma_f32_16x16x32_bf16((a), (b), (c), 0, 0, 0)

// ---------------- cast x (fp32 -> bf16), 8 elems/thread ----------------
__global__ void k_cvt(const float4* __restrict__ in, uint4* __restrict__ out, int n8) {
  int i = blockIdx.x * 256 + threadIdx.x;
  if (i >= n8) return;
  float4 a = in[2 * i], b = in[2 * i + 1];
  uint4 o;
  o.x = f2bf(a.x) | ((u32)f2bf(a.y) << 16);
  o.y = f2bf(a.z) | ((u32)f2bf(a.w) << 16);
  o.z = f2bf(b.x) | ((u32)f2bf(b.y) << 16);
  o.w = f2bf(b.z) | ((u32)f2bf(b.w) << 16);
  out[i] = o;
}

// ---- mask tile flags (all-valid per 64-key tile) + work-queue counter reset ----
__global__ void k_maskflags(const int* __restrict__ mask, u8* __restrict__ flags,
                            u32* __restrict__ ctr) {
  int t = threadIdx.x;  // 64 threads: b = t>>5, kb = t&31
  if (t == 0) *ctr = 0;
  int b = t >> 5, kb = t & 31;
  const int* m = mask + b * Tc + kb * 64;
  int all = 1;
  for (int i = 0; i < 64; ++i) all &= (m[i] != 0);
  flags[b * 32 + kb] = (u8)all;
}

// ------------- transpose + cast weights: in fp32 [R][C] -> out bf16 [C][R] -------------
__global__ __launch_bounds__(256) void k_transpose_w(const float* __restrict__ in,
                                                     u16* __restrict__ out, int R, int C) {
  __shared__ u16 tile[64][65];
  int c0 = blockIdx.x * 64, r0 = blockIdx.y * 64;
  int tx = threadIdx.x, ty = threadIdx.y;  // block (64,4)
  for (int i = ty; i < 64; i += 4)
    tile[i][tx] = f2bf(in[(size_t)(r0 + i) * C + c0 + tx]);
  __syncthreads();
  for (int i = ty; i < 64; i += 4)
    out[(size_t)(c0 + i) * R + r0 + tx] = tile[tx][i];
}

// ------------- transpose V per head: [bh][2048][64] -> VT [bh][64][2048] (bf16) -------------
__global__ __launch_bounds__(256) void k_transpose_v(const u16* __restrict__ V,
                                                     u16* __restrict__ VT) {
  __shared__ u16 tile[64][65];
  int bh = blockIdx.y;
  int t0 = blockIdx.x * 64;
  const u16* src = V + (size_t)bh * Tc * HD;
  u16* dst = VT + (size_t)bh * Tc * HD;
  int tx = threadIdx.x, ty = threadIdx.y;
  for (int i = ty; i < 64; i += 4)
    tile[i][tx] = src[(size_t)(t0 + i) * HD + tx];
  __syncthreads();
  for (int i = ty; i < 64; i += 4)
    dst[(size_t)i * Tc + t0 + tx] = tile[tx][i];
}

// ---------------- GEMM: C = A[M,K] * BT[N,K]^T (+bias), bf16 in, fp32 acc ----------------
// EPI=0: scatter into Qh(scaled)/Kh/Vh per-head bf16 layouts. EPI=1: fp32 out + bias.
template <int EPI>
__global__ __launch_bounds__(256) void k_gemm(const u16* __restrict__ A,
                                              const u16* __restrict__ BTm,
                                              const float* __restrict__ bias,
                                              u16* __restrict__ oQ, u16* __restrict__ oK,
                                              u16* __restrict__ oV, float* __restrict__ oF,
                                              int M, int N, int K) {
  __shared__ u16 As[128 * 32];
  __shared__ u16 Bs[128 * 32];
  const int tid = threadIdx.x;
  const int lane = tid & 63, wave = tid >> 6;
  const int wr = wave >> 1, wc = wave & 1;
  const int row0 = blockIdx.y * 128, col0 = blockIdx.x * 128;

  f32x4 acc[4][4];
#pragma unroll
  for (int m = 0; m < 4; ++m)
#pragma unroll
    for (int n = 0; n < 4; ++n) acc[m][n] = (f32x4)(0.f);

  const int srow = lane >> 2;
  const int sg = lane & 3;
  const int sf = (lane >> 3) & 3;
  const int kfetch = ((sg ^ sf) * 8);

  const int r16 = lane & 15;
  const int g = lane >> 4;
  const int fr = (r16 >> 1) & 3;
  const int koff = ((g ^ fr) * 8);

  for (int k0 = 0; k0 < K; k0 += 32) {
    if (k0) __syncthreads();
#pragma unroll
    for (int p = 0; p < 2; ++p) {
      int seg = wave * 2 + p;
      int row = seg * 16 + srow;
      gl_lds16(A + (size_t)(row0 + row) * K + k0 + kfetch, &As[seg * 512 + lane * 8]);
      gl_lds16(BTm + (size_t)(col0 + row) * K + k0 + kfetch, &Bs[seg * 512 + lane * 8]);
    }
    __syncthreads();
    short8 af[4], bf[4];
#pragma unroll
    for (int m = 0; m < 4; ++m)
      af[m] = *(const short8*)&As[(wr * 64 + m * 16 + r16) * 32 + koff];
#pragma unroll
    for (int n = 0; n < 4; ++n)
      bf[n] = *(const short8*)&Bs[(wc * 64 + n * 16 + r16) * 32 + koff];
#pragma unroll
    for (int m = 0; m < 4; ++m)
#pragma unroll
      for (int n = 0; n < 4; ++n)
        acc[m][n] = MFMA(af[m], bf[n], acc[m][n]);
  }

#pragma unroll
  for (int m = 0; m < 4; ++m) {
    int rowg = row0 + wr * 64 + m * 16 + g * 4;
#pragma unroll
    for (int n = 0; n < 4; ++n) {
      int colg = col0 + wc * 64 + n * 16 + r16;
      float bv = bias[colg];
      if constexpr (EPI == 0) {
        int which = colg / Hc;
        int hc = colg - which * Hc;
        int h = hc >> 6, d = hc & 63;
#pragma unroll
        for (int r = 0; r < 4; ++r) {
          int mg = rowg + r;
          int b = mg >> 11, t = mg & 2047;
          float v = acc[m][n][r] + bv;
          size_t dst = ((size_t)(b * NH + h) * Tc + t) * HD + d;
          if (which == 0)      oQ[dst] = f2bf(v * QSCALE);
          else if (which == 1) oK[dst] = f2bf(v);
          else                 oV[dst] = f2bf(v);
        }
      } else {
#pragma unroll
        for (int r = 0; r < 4; ++r) {
          int mg = rowg + r;
          oF[(size_t)mg * Hc + colg] = acc[m][n][r] + bv;
        }
      }
    }
  }
}

// ---------------- flash attention: work-stealing, 4 waves x 16 q-rows, dbuf staging ----------------
// 768 strips (24 bh x 32 qt of 64 q-rows), queue sorted descending cost (qt=31 first).
// Grid 512 blocks x 256 thr (2/CU, 8 waves/CU, all resident). Per iter: stage(next tile)
// issued BEFORE compute(cur); __syncthreads' implicit vmcnt(0) drain lands after compute.
__global__ __launch_bounds__(256) void k_attn(const u16* __restrict__ Qh,
                                              const u16* __restrict__ Kh,
                                              const u16* __restrict__ VT,
                                              const int* __restrict__ mask,
                                              const u8* __restrict__ flags,
                                              u16* __restrict__ O,
                                              u32* __restrict__ ctr) {
  __shared__ u16 Ks[2][4096];
  __shared__ u16 Vs[2][4096];
  __shared__ u16 Ps[4][1024];
  __shared__ int s_item;
  const int tid = threadIdx.x, lane = tid & 63, wave = tid >> 6;
  const int r16 = lane & 15, g = lane >> 4;
  const int skey = lane >> 3;          // row within 8-row staging segment
  const int sgr = lane & 7;            // 16B granule slot
  const int sgd = ((sgr ^ skey) * 8);  // pre-swizzled source granule (elems)

  for (;;) {
    if (tid == 0) s_item = (int)atomicAdd(ctr, 1u);
    __syncthreads();
    const int item = s_item;
    if (item >= NITEMS) break;
    const int qt = 31 - item / NBH;     // descending cost
    const int bh = item % NBH;
    const int b = bh / NH, h = bh - b * NH;
    const int q0 = qt * 64;
    const int nt = qt + 1;
    const int* mrow = mask + b * Tc;
    const u8* frow = flags + b * 32;

    // Q fragments (rows q0 + wave*16 + r16), scale folded in at GEMM1 epilogue
    const u16* qbase = Qh + ((size_t)bh * Tc + q0 + wave * 16 + r16) * HD;
    const short8 qf0 = *(const short8*)(qbase + g * 8);
    const short8 qf1 = *(const short8*)(qbase + 32 + g * 8);

    f32x4 acc[4];
#pragma unroll
    for (int n = 0; n < 4; ++n) acc[n] = (f32x4)(0.f);
    float mrun[4], lrun[4];
#pragma unroll
    for (int r = 0; r < 4; ++r) { mrun[r] = -3.0e38f; lrun[r] = 0.f; }

    // prologue: stage tile 0 into buf 0
#pragma unroll
    for (int p = 0; p < 2; ++p) {
      int seg = wave * 2 + p;
      int rloc = seg * 8 + skey;
      gl_lds16(Kh + ((size_t)bh * Tc + 0 + rloc) * HD + sgd, &Ks[0][seg * 512 + lane * 8]);
      gl_lds16(VT + ((size_t)bh * HD + rloc) * Tc + 0 + sgd, &Vs[0][seg * 512 + lane * 8]);
    }
    __syncthreads();  // drains vmcnt: tile 0 resident

    int cur = 0;
    for (int t = 0; t < nt; ++t) {
      const int kb = t * 64;

      // ---- stage NEXT tile into other buffer (latency hides under compute) ----
      if (t + 1 < nt) {
        const int kb2 = kb + 64;
#pragma unroll
        for (int p = 0; p < 2; ++p) {
          int seg = wave * 2 + p;
          int rloc = seg * 8 + skey;
          gl_lds16(Kh + ((size_t)bh * Tc + kb2 + rloc) * HD + sgd,
                   &Ks[cur ^ 1][seg * 512 + lane * 8]);
          gl_lds16(VT + ((size_t)bh * HD + rloc) * Tc + kb2 + sgd,
                   &Vs[cur ^ 1][seg * 512 + lane * 8]);
        }
      }

      const u16* Kc = &Ks[cur][0];
      const u16* Vc = &Vs[cur][0];

      // ---- S = Q K^T ----
      f32x4 s[4];
#pragma unroll
      for (int n = 0; n < 4; ++n) {
        int key = n * 16 + r16;
        int k7 = key & 7;
        short8 kf0 = *(const short8*)&Kc[key * 64 + ((g ^ k7) * 8)];
        short8 kf1 = *(const short8*)&Kc[key * 64 + (((4 + g) ^ k7) * 8)];
        f32x4 z = (f32x4)(0.f);
        z = MFMA(qf0, kf0, z);
        z = MFMA(qf1, kf1, z);
        s[n] = z;
      }

      // ---- masking: skip entirely for interior all-valid tiles ----
      const bool diag = (t == nt - 1);
      if (diag || !frow[t]) {
        const int fl = frow[t];
#pragma unroll
        for (int n = 0; n < 4; ++n) {
          int keyg = kb + n * 16 + r16;
          int km = fl ? 1 : mrow[keyg];
#pragma unroll
          for (int r = 0; r < 4; ++r) {
            bool ok = (km != 0);
            if (diag) ok = ok && (keyg <= q0 + wave * 16 + g * 4 + r);
            if (!ok) s[n][r] = -3.0e38f;
          }
        }
      }

      // ---- online softmax (base-2 domain) ----
      float alpha[4];
#pragma unroll
      for (int r = 0; r < 4; ++r) {
        float v = fmaxf(fmaxf(s[0][r], s[1][r]), fmaxf(s[2][r], s[3][r]));
        v = fmaxf(v, __shfl_xor(v, 1));
        v = fmaxf(v, __shfl_xor(v, 2));
        v = fmaxf(v, __shfl_xor(v, 4));
        v = fmaxf(v, __shfl_xor(v, 8));
        float nm = fmaxf(mrun[r], v);
        alpha[r] = fexp2(mrun[r] - nm);
        mrun[r] = nm;
      }
      float rs[4] = {0.f, 0.f, 0.f, 0.f};
#pragma unroll
      for (int n = 0; n < 4; ++n)
#pragma unroll
        for (int r = 0; r < 4; ++r) {
          float p = fexp2(s[n][r] - mrun[r]);
          s[n][r] = p;
          rs[r] += p;
        }
#pragma unroll
      for (int r = 0; r < 4; ++r) {
        float v = rs[r];
        v += __shfl_xor(v, 1);
        v += __shfl_xor(v, 2);
        v += __shfl_xor(v, 4);
        v += __shfl_xor(v, 8);
        lrun[r] = lrun[r] * alpha[r] + v;
        acc[0][r] *= alpha[r];
        acc[1][r] *= alpha[r];
        acc[2][r] *= alpha[r];
        acc[3][r] *= alpha[r];
      }

      // ---- P (bf16) -> per-wave swizzled LDS, read back as A-frags ----
      u16* pw = &Ps[wave][0];
#pragma unroll
      for (int n = 0; n < 4; ++n) {
        int key = n * 16 + r16;
        int gk = key >> 3;
#pragma unroll
        for (int r = 0; r < 4; ++r) {
          int q = g * 4 + r;
          pw[q * 64 + ((gk ^ (q & 7)) * 8) + (key & 7)] = f2bf(s[n][r]);
        }
      }
      asm volatile("s_waitcnt lgkmcnt(0)" ::: "memory");
      short8 pa0, pa1;
      {
        int q7 = r16 & 7;
        pa0 = *(const short8*)&pw[r16 * 64 + ((g ^ q7) * 8)];
        pa1 = *(const short8*)&pw[r16 * 64 + (((4 + g) ^ q7) * 8)];
      }

      // ---- O += P V ----
#pragma unroll
      for (int n = 0; n < 4; ++n) {
        int d = n * 16 + r16;
        int d7 = d & 7;
        short8 vf0 = *(const short8*)&Vc[d * 64 + ((g ^ d7) * 8)];
        short8 vf1 = *(const short8*)&Vc[d * 64 + (((4 + g) ^ d7) * 8)];
        acc[n] = MFMA(pa0, vf0, acc[n]);
        acc[n] = MFMA(pa1, vf1, acc[n]);
      }

      __syncthreads();  // implicit vmcnt(0)+lgkmcnt(0): next-tile staging resident
      cur ^= 1;
    }

    // ---- normalize + write O[b][t][h*64+d] (bf16) ----
#pragma unroll
    for (int r = 0; r < 4; ++r) {
      int qg = q0 + wave * 16 + g * 4 + r;
      float inv = 1.0f / lrun[r];
      u16* orow = O + ((size_t)(b * Tc + qg)) * Hc + h * 64;
#pragma unroll
      for (int n = 0; n < 4; ++n) orow[n * 16 + r16] = f2bf(acc[n][r] * inv);
    }
  }
}

// ---------------- launch ----------------
extern "C" void kernel_launch(void* const* d_in, const int* in_sizes, int n_in,
                              void* d_out, int out_size, void* d_ws, size_t ws_size,
                              hipStream_t stream) {
  const float* x = (const float*)d_in[0];
  const int* mask = (const int*)d_in[1];
  const float* Wqkv = (const float*)d_in[2];
  const float* bqkv = (const float*)d_in[3];
  const float* Wproj = (const float*)d_in[4];
  const float* bproj = (const float*)d_in[5];
  float* out = (float*)d_out;

  char* ws = (char*)d_ws;
  size_t off = 0;
  auto alloc = [&](size_t bytes) {
    char* p = ws + off;
    off += (bytes + 255) & ~(size_t)255;
    return p;
  };
  u16* xb     = (u16*)alloc((size_t)BTc * Hc * 2);
  u16* WqkvT  = (u16*)alloc((size_t)N3 * Hc * 2);
  u16* WprojT = (u16*)alloc((size_t)Hc * Hc * 2);
  u16* Qh     = (u16*)alloc((size_t)BTc * Hc * 2);
  u16* Kh     = (u16*)alloc((size_t)BTc * Hc * 2);
  u16* Vh     = (u16*)alloc((size_t)BTc * Hc * 2);
  u16* VT     = (u16*)alloc((size_t)BTc * Hc * 2);
  u32* ctr    = (u32*)alloc(256);
  u8*  flags  = (u8*)alloc(256);
  u16* Ob     = xb;  // alias: xb dead after GEMM1, reused for attention output

  int n8 = BTc * Hc / 8;
  k_cvt<<<(n8 + 255) / 256, 256, 0, stream>>>((const float4*)x, (uint4*)xb, n8);
  k_maskflags<<<1, 64, 0, stream>>>(mask, flags, ctr);
  k_transpose_w<<<dim3(N3 / 64, Hc / 64), dim3(64, 4), 0, stream>>>(Wqkv, WqkvT, Hc, N3);
  k_transpose_w<<<dim3(Hc / 64, Hc / 64), dim3(64, 4), 0, stream>>>(Wproj, WprojT, Hc, Hc);
  k_gemm<0><<<dim3(N3 / 128, BTc / 128), 256, 0, stream>>>(xb, WqkvT, bqkv, Qh, Kh, Vh,
                                                           nullptr, BTc, N3, Hc);
  k_transpose_v<<<dim3(Tc / 64, Bc * NH), dim3(64, 4), 0, stream>>>(Vh, VT);
  k_attn<<<dim3(512), 256, 0, stream>>>(Qh, Kh, VT, mask, flags, Ob, ctr);
  k_gemm<1><<<dim3(Hc / 128, BTc / 128), 256, 0, stream>>>(Ob, WprojT, bproj, nullptr,
                                                           nullptr, nullptr, out, BTc, Hc, Hc);
}

// Round 4
// 137.934 us; speedup vs baseline: 1.7621x; 1.0357x over previous
//
#include <hip/hip_runtime.h>
#include <stdint.h>

typedef unsigned short u16;
typedef unsigned int   u32;
typedef unsigned char  u8;
typedef __attribute__((ext_vector_type(8))) short short8;
typedef __attribute__((ext_vector_type(4))) float f32x4;

#define DEV static __device__ __forceinline__

static constexpr int Bc = 2, Tc = 2048, Hc = 768, NH = 12, HD = 64;
static constexpr int BTc = Bc * Tc;      // 4096 rows
static constexpr int N3 = 3 * Hc;        // 2304
static constexpr int NBH = Bc * NH;      // 24
static constexpr int NITEMS = 32 * NBH;  // 768 work items (64-row q strips)
static constexpr float QSCALE = 0.125f * 1.44269504088896f; // 1/sqrt(64) * log2(e)

DEV u16 f2bf(float f) {
  u32 u = __float_as_uint(f);
  u32 r = (u + 0x7fffu + ((u >> 16) & 1u)) >> 16;  // RNE
  return (u16)r;
}

DEV float fexp2(float x) {
#if __has_builtin(__builtin_amdgcn_exp2f)
  return __builtin_amdgcn_exp2f(x);
#else
  return exp2f(x);
#endif
}

DEV u32 cvtpk_bf16(float lo, float hi) {  // packs 2 f32 -> 2 bf16 (RNE), 1 VALU op
  u32 r;
  asm("v_cvt_pk_bf16_f32 %0, %1, %2" : "=v"(r) : "v"(lo), "v"(hi));
  return r;
}

// DPP cross-lane at VALU rate (no LDS pipe). Reduce over the 16-lane row.
template <int CTRL>
DEV float dppf(float x) {
  return __int_as_float(__builtin_amdgcn_update_dpp(
      __float_as_int(x), __float_as_int(x), CTRL, 0xf, 0xf, false));
}
DEV float rowmax16(float v) {   // full max across lanes 16g..16g+15
  v = fmaxf(v, dppf<0xB1>(v));   // quad_perm xor1
  v = fmaxf(v, dppf<0x4E>(v));   // quad_perm xor2
  v = fmaxf(v, dppf<0x124>(v));  // row_ror:4
  v = fmaxf(v, dppf<0x128>(v));  // row_ror:8
  return v;
}
DEV float rowsum16(float v) {
  v += dppf<0xB1>(v);
  v += dppf<0x4E>(v);
  v += dppf<0x124>(v);
  v += dppf<0x128>(v);
  return v;
}

DEV void gl_lds16(const u16* g, u16* l) {
  __builtin_amdgcn_global_load_lds(
      (const __attribute__((address_space(1))) u32*)g,
      (__attribute__((address_space(3))) u32*)l, 16, 0, 0);
}

#define MFMA(a, b, c) __builtin_amdgcn_mfma_f32_16x16x32_bf16((a), (b), (c), 0, 0, 0)

// ---------------- cast x (fp32 -> bf16), 8 elems/thread ----------------
__global__ void k_cvt(const float4* __restrict__ in, uint4* __restrict__ out, int n8) {
  int i = blockIdx.x * 256 + threadIdx.x;
  if (i >= n8) return;
  float4 a = in[2 * i], b = in[2 * i + 1];
  uint4 o;
  o.x = f2bf(a.x) | ((u32)f2bf(a.y) << 16);
  o.y = f2bf(a.z) | ((u32)f2bf(a.w) << 16);
  o.z = f2bf(b.x) | ((u32)f2bf(b.y) << 16);
  o.w = f2bf(b.z) | ((u32)f2bf(b.w) << 16);
  out[i] = o;
}

// ---- mask tile flags (all-valid per 64-key tile) + work-queue counter reset ----
__global__ void k_maskflags(const int* __restrict__ mask, u8* __restrict__ flags,
                            u32* __restrict__ ctr) {
  int t = threadIdx.x;  // 64 threads: b = t>>5, kb = t&31
  if (t == 0) *ctr = 0;
  int b = t >> 5, kb = t & 31;
  const int* m = mask + b * Tc + kb * 64;
  int all = 1;
  for (int i = 0; i < 64; ++i) all &= (m[i] != 0);
  flags[b * 32 + kb] = (u8)all;
}

// ------------- transpose + cast weights: in fp32 [R][C] -> out bf16 [C][R] -------------
__global__ __launch_bounds__(256) void k_transpose_w(const float* __restrict__ in,
                                                     u16* __restrict__ out, int R, int C) {
  __shared__ u16 tile[64][65];
  int c0 = blockIdx.x * 64, r0 = blockIdx.y * 64;
  int tx = threadIdx.x, ty = threadIdx.y;  // block (64,4)
  for (int i = ty; i < 64; i += 4)
    tile[i][tx] = f2bf(in[(size_t)(r0 + i) * C + c0 + tx]);
  __syncthreads();
  for (int i = ty; i < 64; i += 4)
    out[(size_t)(c0 + i) * R + r0 + tx] = tile[tx][i];
}

// ------------- transpose V per head: [bh][2048][64] -> VT [bh][64][2048] (bf16) -------------
__global__ __launch_bounds__(256) void k_transpose_v(const u16* __restrict__ V,
                                                     u16* __restrict__ VT) {
  __shared__ u16 tile[64][65];
  int bh = blockIdx.y;
  int t0 = blockIdx.x * 64;
  const u16* src = V + (size_t)bh * Tc * HD;
  u16* dst = VT + (size_t)bh * Tc * HD;
  int tx = threadIdx.x, ty = threadIdx.y;
  for (int i = ty; i < 64; i += 4)
    tile[i][tx] = src[(size_t)(t0 + i) * HD + tx];
  __syncthreads();
  for (int i = ty; i < 64; i += 4)
    dst[(size_t)i * Tc + t0 + tx] = tile[tx][i];
}

// ---------------- GEMM: C = A[M,K] * BT[N,K]^T (+bias), bf16 in, fp32 acc ----------------
template <int EPI>
__global__ __launch_bounds__(256) void k_gemm(const u16* __restrict__ A,
                                              const u16* __restrict__ BTm,
                                              const float* __restrict__ bias,
                                              u16* __restrict__ oQ, u16* __restrict__ oK,
                                              u16* __restrict__ oV, float* __restrict__ oF,
                                              int M, int N, int K) {
  __shared__ u16 As[128 * 32];
  __shared__ u16 Bs[128 * 32];
  const int tid = threadIdx.x;
  const int lane = tid & 63, wave = tid >> 6;
  const int wr = wave >> 1, wc = wave & 1;
  const int row0 = blockIdx.y * 128, col0 = blockIdx.x * 128;

  f32x4 acc[4][4];
#pragma unroll
  for (int m = 0; m < 4; ++m)
#pragma unroll
    for (int n = 0; n < 4; ++n) acc[m][n] = (f32x4)(0.f);

  const int srow = lane >> 2;
  const int sg = lane & 3;
  const int sf = (lane >> 3) & 3;
  const int kfetch = ((sg ^ sf) * 8);

  const int r16 = lane & 15;
  const int g = lane >> 4;
  const int fr = (r16 >> 1) & 3;
  const int koff = ((g ^ fr) * 8);

  for (int k0 = 0; k0 < K; k0 += 32) {
    if (k0) __syncthreads();
#pragma unroll
    for (int p = 0; p < 2; ++p) {
      int seg = wave * 2 + p;
      int row = seg * 16 + srow;
      gl_lds16(A + (size_t)(row0 + row) * K + k0 + kfetch, &As[seg * 512 + lane * 8]);
      gl_lds16(BTm + (size_t)(col0 + row) * K + k0 + kfetch, &Bs[seg * 512 + lane * 8]);
    }
    __syncthreads();
    short8 af[4], bf[4];
#pragma unroll
    for (int m = 0; m < 4; ++m)
      af[m] = *(const short8*)&As[(wr * 64 + m * 16 + r16) * 32 + koff];
#pragma unroll
    for (int n = 0; n < 4; ++n)
      bf[n] = *(const short8*)&Bs[(wc * 64 + n * 16 + r16) * 32 + koff];
#pragma unroll
    for (int m = 0; m < 4; ++m)
#pragma unroll
      for (int n = 0; n < 4; ++n)
        acc[m][n] = MFMA(af[m], bf[n], acc[m][n]);
  }

#pragma unroll
  for (int m = 0; m < 4; ++m) {
    int rowg = row0 + wr * 64 + m * 16 + g * 4;
#pragma unroll
    for (int n = 0; n < 4; ++n) {
      int colg = col0 + wc * 64 + n * 16 + r16;
      float bv = bias[colg];
      if constexpr (EPI == 0) {
        int which = colg / Hc;
        int hc = colg - which * Hc;
        int h = hc >> 6, d = hc & 63;
#pragma unroll
        for (int r = 0; r < 4; ++r) {
          int mg = rowg + r;
          int b = mg >> 11, t = mg & 2047;
          float v = acc[m][n][r] + bv;
          size_t dst = ((size_t)(b * NH + h) * Tc + t) * HD + d;
          if (which == 0)      oQ[dst] = f2bf(v * QSCALE);
          else if (which == 1) oK[dst] = f2bf(v);
          else                 oV[dst] = f2bf(v);
        }
      } else {
#pragma unroll
        for (int r = 0; r < 4; ++r) {
          int mg = rowg + r;
          oF[(size_t)mg * Hc + colg] = acc[m][n][r] + bv;
        }
      }
    }
  }
}

// ---------------- flash attention: work-stealing, 4 waves x 16 q-rows, dbuf staging ----------------
// LDS exactly 40960B (= 160KB/4 -> 4 blocks/CU); s_item aliased into Ps[0][0..1]
// (safe: >=1 barrier between the s_item read and the first P-write; no Ps access
// between the last tile's barrier and the next s_item write).
// Softmax reduces via DPP (VALU rate); defer-rescale (T13) skips alpha most tiles.
__global__ __launch_bounds__(256) void k_attn(const u16* __restrict__ Qh,
                                              const u16* __restrict__ Kh,
                                              const u16* __restrict__ VT,
                                              const int* __restrict__ mask,
                                              const u8* __restrict__ flags,
                                              u16* __restrict__ O,
                                              u32* __restrict__ ctr) {
  __shared__ u16 Ks[2][4096];
  __shared__ u16 Vs[2][4096];
  __shared__ u16 Ps[4][1024];
  volatile int* s_item = (volatile int*)&Ps[0][0];
  const int tid = threadIdx.x, lane = tid & 63, wave = tid >> 6;
  const int r16 = lane & 15, g = lane >> 4;
  const int skey = lane >> 3;          // row within 8-row staging segment
  const int sgr = lane & 7;            // 16B granule slot
  const int sgd = ((sgr ^ skey) * 8);  // pre-swizzled source granule (elems)

  for (;;) {
    if (tid == 0) *s_item = (int)atomicAdd(ctr, 1u);
    __syncthreads();
    const int item = *s_item;
    if (item >= NITEMS) break;
    const int qt = 31 - item / NBH;     // descending cost
    const int bh = item % NBH;
    const int b = bh / NH, h = bh - b * NH;
    const int q0 = qt * 64;
    const int nt = qt + 1;
    const int* mrow = mask + b * Tc;
    const u8* frow = flags + b * 32;

    const u16* qbase = Qh + ((size_t)bh * Tc + q0 + wave * 16 + r16) * HD;
    const short8 qf0 = *(const short8*)(qbase + g * 8);
    const short8 qf1 = *(const short8*)(qbase + 32 + g * 8);

    f32x4 acc[4];
#pragma unroll
    for (int n = 0; n < 4; ++n) acc[n] = (f32x4)(0.f);
    float mrun[4], lrun[4];
#pragma unroll
    for (int r = 0; r < 4; ++r) { mrun[r] = -3.0e38f; lrun[r] = 0.f; }

    // prologue: stage tile 0 into buf 0
#pragma unroll
    for (int p = 0; p < 2; ++p) {
      int seg = wave * 2 + p;
      int rloc = seg * 8 + skey;
      gl_lds16(Kh + ((size_t)bh * Tc + 0 + rloc) * HD + sgd, &Ks[0][seg * 512 + lane * 8]);
      gl_lds16(VT + ((size_t)bh * HD + rloc) * Tc + 0 + sgd, &Vs[0][seg * 512 + lane * 8]);
    }
    __syncthreads();  // drains vmcnt: tile 0 resident (also orders s_item reads)

    int cur = 0;
    for (int t = 0; t < nt; ++t) {
      const int kb = t * 64;

      // ---- stage NEXT tile into other buffer ----
      if (t + 1 < nt) {
        const int kb2 = kb + 64;
#pragma unroll
        for (int p = 0; p < 2; ++p) {
          int seg = wave * 2 + p;
          int rloc = seg * 8 + skey;
          gl_lds16(Kh + ((size_t)bh * Tc + kb2 + rloc) * HD + sgd,
                   &Ks[cur ^ 1][seg * 512 + lane * 8]);
          gl_lds16(VT + ((size_t)bh * HD + rloc) * Tc + kb2 + sgd,
                   &Vs[cur ^ 1][seg * 512 + lane * 8]);
        }
      }

      const u16* Kc = &Ks[cur][0];
      const u16* Vc = &Vs[cur][0];

      // ---- S = Q K^T ----
      f32x4 s[4];
#pragma unroll
      for (int n = 0; n < 4; ++n) {
        int key = n * 16 + r16;
        int k7 = key & 7;
        short8 kf0 = *(const short8*)&Kc[key * 64 + ((g ^ k7) * 8)];
        short8 kf1 = *(const short8*)&Kc[key * 64 + (((4 + g) ^ k7) * 8)];
        f32x4 z = (f32x4)(0.f);
        z = MFMA(qf0, kf0, z);
        z = MFMA(qf1, kf1, z);
        s[n] = z;
      }

      // ---- masking: skip entirely for interior all-valid tiles ----
      const bool diag = (t == nt - 1);
      if (diag || !frow[t]) {
        const int fl = frow[t];
#pragma unroll
        for (int n = 0; n < 4; ++n) {
          int keyg = kb + n * 16 + r16;
          int km = fl ? 1 : mrow[keyg];
#pragma unroll
          for (int r = 0; r < 4; ++r) {
            bool ok = (km != 0);
            if (diag) ok = ok && (keyg <= q0 + wave * 16 + g * 4 + r);
            if (!ok) s[n][r] = -3.0e38f;
          }
        }
      }

      // ---- online softmax (base-2 domain), DPP reduces + defer-rescale ----
      float tmax[4];
#pragma unroll
      for (int r = 0; r < 4; ++r)
        tmax[r] = rowmax16(fmaxf(fmaxf(s[0][r], s[1][r]), fmaxf(s[2][r], s[3][r])));
      bool defer = (tmax[0] <= mrun[0] + 8.0f) & (tmax[1] <= mrun[1] + 8.0f) &
                   (tmax[2] <= mrun[2] + 8.0f) & (tmax[3] <= mrun[3] + 8.0f);
      if (!__all(defer)) {
#pragma unroll
        for (int r = 0; r < 4; ++r) {
          float nm = fmaxf(mrun[r], tmax[r]);
          float alpha = fexp2(mrun[r] - nm);
          mrun[r] = nm;
          lrun[r] *= alpha;
          acc[0][r] *= alpha;
          acc[1][r] *= alpha;
          acc[2][r] *= alpha;
          acc[3][r] *= alpha;
        }
      }
      float rs[4] = {0.f, 0.f, 0.f, 0.f};
#pragma unroll
      for (int n = 0; n < 4; ++n)
#pragma unroll
        for (int r = 0; r < 4; ++r) {
          float p = fexp2(s[n][r] - mrun[r]);
          s[n][r] = p;
          rs[r] += p;
        }
#pragma unroll
      for (int r = 0; r < 4; ++r) lrun[r] += rowsum16(rs[r]);

      // ---- P (bf16 via cvt_pk) -> per-wave swizzled LDS, read back as A-frags ----
      u16* pw = &Ps[wave][0];
#pragma unroll
      for (int n = 0; n < 4; ++n) {
        int key = n * 16 + r16;
        int gk = key >> 3;
        int k7 = key & 7;
        u32 p01 = cvtpk_bf16(s[n][0], s[n][1]);
        u32 p23 = cvtpk_bf16(s[n][2], s[n][3]);
        int q0l = g * 4;
        pw[(q0l + 0) * 64 + ((gk ^ ((q0l + 0) & 7)) * 8) + k7] = (u16)p01;
        pw[(q0l + 1) * 64 + ((gk ^ ((q0l + 1) & 7)) * 8) + k7] = (u16)(p01 >> 16);
        pw[(q0l + 2) * 64 + ((gk ^ ((q0l + 2) & 7)) * 8) + k7] = (u16)p23;
        pw[(q0l + 3) * 64 + ((gk ^ ((q0l + 3) & 7)) * 8) + k7] = (u16)(p23 >> 16);
      }
      asm volatile("s_waitcnt lgkmcnt(0)" ::: "memory");
      short8 pa0, pa1;
      {
        int q7 = r16 & 7;
        pa0 = *(const short8*)&pw[r16 * 64 + ((g ^ q7) * 8)];
        pa1 = *(const short8*)&pw[r16 * 64 + (((4 + g) ^ q7) * 8)];
      }

      // ---- O += P V ----
#pragma unroll
      for (int n = 0; n < 4; ++n) {
        int d = n * 16 + r16;
        int d7 = d & 7;
        short8 vf0 = *(const short8*)&Vc[d * 64 + ((g ^ d7) * 8)];
        short8 vf1 = *(const short8*)&Vc[d * 64 + (((4 + g) ^ d7) * 8)];
        acc[n] = MFMA(pa0, vf0, acc[n]);
        acc[n] = MFMA(pa1, vf1, acc[n]);
      }

      __syncthreads();  // next-tile staging resident; Ps reads complete
      cur ^= 1;
    }

    // ---- normalize + write O[b][t][h*64+d] (bf16) ----
#pragma unroll
    for (int r = 0; r < 4; ++r) {
      int qg = q0 + wave * 16 + g * 4 + r;
      float inv = 1.0f / lrun[r];
      u16* orow = O + ((size_t)(b * Tc + qg)) * Hc + h * 64;
#pragma unroll
      for (int n = 0; n < 4; ++n) orow[n * 16 + r16] = f2bf(acc[n][r] * inv);
    }
  }
}

// ---------------- launch ----------------
extern "C" void kernel_launch(void* const* d_in, const int* in_sizes, int n_in,
                              void* d_out, int out_size, void* d_ws, size_t ws_size,
                              hipStream_t stream) {
  const float* x = (const float*)d_in[0];
  const int* mask = (const int*)d_in[1];
  const float* Wqkv = (const float*)d_in[2];
  const float* bqkv = (const float*)d_in[3];
  const float* Wproj = (const float*)d_in[4];
  const float* bproj = (const float*)d_in[5];
  float* out = (float*)d_out;

  char* ws = (char*)d_ws;
  size_t off = 0;
  auto alloc = [&](size_t bytes) {
    char* p = ws + off;
    off += (bytes + 255) & ~(size_t)255;
    return p;
  };
  u16* xb     = (u16*)alloc((size_t)BTc * Hc * 2);
  u16* WqkvT  = (u16*)alloc((size_t)N3 * Hc * 2);
  u16* WprojT = (u16*)alloc((size_t)Hc * Hc * 2);
  u16* Qh     = (u16*)alloc((size_t)BTc * Hc * 2);
  u16* Kh     = (u16*)alloc((size_t)BTc * Hc * 2);
  u16* Vh     = (u16*)alloc((size_t)BTc * Hc * 2);
  u16* VT     = (u16*)alloc((size_t)BTc * Hc * 2);
  u32* ctr    = (u32*)alloc(256);
  u8*  flags  = (u8*)alloc(256);
  u16* Ob     = xb;  // alias: xb dead after GEMM1, reused for attention output

  int n8 = BTc * Hc / 8;
  k_cvt<<<(n8 + 255) / 256, 256, 0, stream>>>((const float4*)x, (uint4*)xb, n8);
  k_maskflags<<<1, 64, 0, stream>>>(mask, flags, ctr);
  k_transpose_w<<<dim3(N3 / 64, Hc / 64), dim3(64, 4), 0, stream>>>(Wqkv, WqkvT, Hc, N3);
  k_transpose_w<<<dim3(Hc / 64, Hc / 64), dim3(64, 4), 0, stream>>>(Wproj, WprojT, Hc, Hc);
  k_gemm<0><<<dim3(N3 / 128, BTc / 128), 256, 0, stream>>>(xb, WqkvT, bqkv, Qh, Kh, Vh,
                                                           nullptr, BTc, N3, Hc);
  k_transpose_v<<<dim3(Tc / 64, Bc * NH), dim3(64, 4), 0, stream>>>(Vh, VT);
  k_attn<<<dim3(1024), 256, 0, stream>>>(Qh, Kh, VT, mask, flags, Ob, ctr);
  k_gemm<1><<<dim3(Hc / 128, BTc / 128), 256, 0, stream>>>(Ob, WprojT, bproj, nullptr,
                                                           nullptr, nullptr, out, BTc, Hc, Hc);
}

// Round 5
// 121.787 us; speedup vs baseline: 1.9958x; 1.1326x over previous
//
#include <hip/hip_runtime.h>
#include <stdint.h>

typedef unsigned short u16;
typedef unsigned int   u32;
typedef unsigned char  u8;
typedef __attribute__((ext_vector_type(8))) short short8;
typedef __attribute__((ext_vector_type(4))) float f32x4;
typedef __attribute__((ext_vector_type(4))) unsigned short u16x4;

#define DEV static __device__ __forceinline__

static constexpr int Bc = 2, Tc = 2048, Hc = 768, NH = 12, HD = 64;
static constexpr int BTc = Bc * Tc;      // 4096 rows
static constexpr int N3 = 3 * Hc;        // 2304
static constexpr int NBH = Bc * NH;      // 24
static constexpr int NITEMS = 32 * NBH;  // 768 work items (64-row q strips)
static constexpr float QSCALE = 0.125f * 1.44269504088896f; // 1/sqrt(64) * log2(e)

DEV u16 f2bf(float f) {
  u32 u = __float_as_uint(f);
  u32 r = (u + 0x7fffu + ((u >> 16) & 1u)) >> 16;  // RNE
  return (u16)r;
}

DEV float fexp2(float x) {
#if __has_builtin(__builtin_amdgcn_exp2f)
  return __builtin_amdgcn_exp2f(x);
#else
  return exp2f(x);
#endif
}

DEV u32 cvtpk_bf16(float lo, float hi) {  // packs 2 f32 -> 2 bf16 (RNE), 1 VALU op
  u32 r;
  asm("v_cvt_pk_bf16_f32 %0, %1, %2" : "=v"(r) : "v"(lo), "v"(hi));
  return r;
}

// DPP cross-lane at VALU rate (no LDS pipe). Reduce over the 16-lane row group.
template <int CTRL>
DEV float dppf(float x) {
  return __int_as_float(__builtin_amdgcn_update_dpp(
      __float_as_int(x), __float_as_int(x), CTRL, 0xf, 0xf, false));
}
DEV float rowmax16(float v) {
  v = fmaxf(v, dppf<0xB1>(v));   // quad_perm xor1
  v = fmaxf(v, dppf<0x4E>(v));   // quad_perm xor2
  v = fmaxf(v, dppf<0x124>(v));  // row_ror:4
  v = fmaxf(v, dppf<0x128>(v));  // row_ror:8
  return v;
}
DEV float rowsum16(float v) {
  v += dppf<0xB1>(v);
  v += dppf<0x4E>(v);
  v += dppf<0x124>(v);
  v += dppf<0x128>(v);
  return v;
}

DEV void gl_lds16(const u16* g, u16* l) {
  __builtin_amdgcn_global_load_lds(
      (const __attribute__((address_space(1))) u32*)g,
      (__attribute__((address_space(3))) u32*)l, 16, 0, 0);
}

#define MFMA(a, b, c) __builtin_amdgcn_mfma_f32_16x16x32_bf16((a), (b), (c), 0, 0, 0)

// ---------------- cast x (fp32 -> bf16) + mask flags + queue counter reset ----------------
__global__ void k_cvt(const float4* __restrict__ in, uint4* __restrict__ out, int n8,
                      const int* __restrict__ mask, u8* __restrict__ flags,
                      u32* __restrict__ ctr) {
  if (blockIdx.x == 0 && threadIdx.x < 64) {
    int t = threadIdx.x;  // b = t>>5, kb = t&31
    if (t == 0) *ctr = 0;
    int b = t >> 5, kb = t & 31;
    const int* m = mask + b * Tc + kb * 64;
    int all = 1;
    for (int i = 0; i < 64; ++i) all &= (m[i] != 0);
    flags[b * 32 + kb] = (u8)all;
  }
  int i = blockIdx.x * 256 + threadIdx.x;
  if (i >= n8) return;
  float4 a = in[2 * i], b = in[2 * i + 1];
  uint4 o;
  o.x = f2bf(a.x) | ((u32)f2bf(a.y) << 16);
  o.y = f2bf(a.z) | ((u32)f2bf(a.w) << 16);
  o.z = f2bf(b.x) | ((u32)f2bf(b.y) << 16);
  o.w = f2bf(b.z) | ((u32)f2bf(b.w) << 16);
  out[i] = o;
}

// ------------- transpose + cast weights: in fp32 [R][C] -> out bf16 [C][R] -------------
__global__ __launch_bounds__(256) void k_transpose_w(const float* __restrict__ in,
                                                     u16* __restrict__ out, int R, int C) {
  __shared__ u16 tile[64][65];
  int c0 = blockIdx.x * 64, r0 = blockIdx.y * 64;
  int tx = threadIdx.x, ty = threadIdx.y;  // block (64,4)
  for (int i = ty; i < 64; i += 4)
    tile[i][tx] = f2bf(in[(size_t)(r0 + i) * C + c0 + tx]);
  __syncthreads();
  for (int i = ty; i < 64; i += 4)
    out[(size_t)(c0 + i) * R + r0 + tx] = tile[tx][i];
}

// ---------------- GEMM: C = A[M,K] * BT[N,K]^T (+bias), bf16 in, fp32 acc ----------------
// EPI=0: scatter Q(scaled)/K into [bh][t][d]; V directly TRANSPOSED into VT [bh][d][t].
// EPI=1: fp32 out + bias.
template <int EPI>
__global__ __launch_bounds__(256) void k_gemm(const u16* __restrict__ A,
                                              const u16* __restrict__ BTm,
                                              const float* __restrict__ bias,
                                              u16* __restrict__ oQ, u16* __restrict__ oK,
                                              u16* __restrict__ oV, float* __restrict__ oF,
                                              int M, int N, int K) {
  __shared__ u16 As[128 * 32];
  __shared__ u16 Bs[128 * 32];
  const int tid = threadIdx.x;
  const int lane = tid & 63, wave = tid >> 6;
  const int wr = wave >> 1, wc = wave & 1;
  const int row0 = blockIdx.y * 128, col0 = blockIdx.x * 128;

  f32x4 acc[4][4];
#pragma unroll
  for (int m = 0; m < 4; ++m)
#pragma unroll
    for (int n = 0; n < 4; ++n) acc[m][n] = (f32x4)(0.f);

  const int srow = lane >> 2;
  const int sg = lane & 3;
  const int sf = (lane >> 3) & 3;
  const int kfetch = ((sg ^ sf) * 8);

  const int r16 = lane & 15;
  const int g = lane >> 4;
  const int fr = (r16 >> 1) & 3;
  const int koff = ((g ^ fr) * 8);

  for (int k0 = 0; k0 < K; k0 += 32) {
    if (k0) __syncthreads();
#pragma unroll
    for (int p = 0; p < 2; ++p) {
      int seg = wave * 2 + p;
      int row = seg * 16 + srow;
      gl_lds16(A + (size_t)(row0 + row) * K + k0 + kfetch, &As[seg * 512 + lane * 8]);
      gl_lds16(BTm + (size_t)(col0 + row) * K + k0 + kfetch, &Bs[seg * 512 + lane * 8]);
    }
    __syncthreads();
    short8 af[4], bf[4];
#pragma unroll
    for (int m = 0; m < 4; ++m)
      af[m] = *(const short8*)&As[(wr * 64 + m * 16 + r16) * 32 + koff];
#pragma unroll
    for (int n = 0; n < 4; ++n)
      bf[n] = *(const short8*)&Bs[(wc * 64 + n * 16 + r16) * 32 + koff];
#pragma unroll
    for (int m = 0; m < 4; ++m)
#pragma unroll
      for (int n = 0; n < 4; ++n)
        acc[m][n] = MFMA(af[m], bf[n], acc[m][n]);
  }

#pragma unroll
  for (int m = 0; m < 4; ++m) {
    int rowg = row0 + wr * 64 + m * 16 + g * 4;
#pragma unroll
    for (int n = 0; n < 4; ++n) {
      int colg = col0 + wc * 64 + n * 16 + r16;
      float bv = bias[colg];
      if constexpr (EPI == 0) {
        int which = colg / Hc;
        int hc = colg - which * Hc;
        int h = hc >> 6, d = hc & 63;
        int b = rowg >> 11, t0 = rowg & 2047;  // same b for r=0..3 (128-row tiles)
        if (which == 2) {
          // V -> VT [bh][d][t], 4 consecutive t per lane -> one 8B store
          u16x4 pk;
#pragma unroll
          for (int r = 0; r < 4; ++r) pk[r] = f2bf(acc[m][n][r] + bv);
          *(u16x4*)&oV[((size_t)(b * NH + h) * HD + d) * Tc + t0] = pk;
        } else {
#pragma unroll
          for (int r = 0; r < 4; ++r) {
            float v = acc[m][n][r] + bv;
            size_t dst = ((size_t)(b * NH + h) * Tc + t0 + r) * HD + d;
            if (which == 0) oQ[dst] = f2bf(v * QSCALE);
            else            oK[dst] = f2bf(v);
          }
        }
      } else {
#pragma unroll
        for (int r = 0; r < 4; ++r)
          oF[(size_t)(rowg + r) * Hc + colg] = acc[m][n][r] + bv;
      }
    }
  }
}

// ---------------- flash attention: work-stealing + quad-buffered counted-vmcnt pipeline ----
// Grid 512 x 256thr (2 blocks/CU, LDS 72KB). 768 items (qt desc = LPT). Per iter:
//   issue prefetch t+2 -> slot (t+2)&3 ; s_waitcnt vmcnt(8) ; raw s_barrier ; compute t.
// vmcnt(8) leaves tiles t+1,t+2 in flight (FIFO retire => tile t resident). Distance-4
// slot ring makes the prefetch WAR-safe with one barrier (readers finished 2 barriers ago).
__global__ __launch_bounds__(256) void k_attn(const u16* __restrict__ Qh,
                                              const u16* __restrict__ Kh,
                                              const u16* __restrict__ VT,
                                              const int* __restrict__ mask,
                                              const u8* __restrict__ flags,
                                              u16* __restrict__ O,
                                              u32* __restrict__ ctr) {
  __shared__ u16 Ks[4][4096];
  __shared__ u16 Vs[4][4096];
  __shared__ u16 Ps[4][1024];
  __shared__ int s_item;
  const int tid = threadIdx.x, lane = tid & 63, wave = tid >> 6;
  const int r16 = lane & 15, g = lane >> 4;
  const int skey = lane >> 3;          // row within 8-row staging segment
  const int sgr = lane & 7;            // 16B granule slot
  const int sgd = ((sgr ^ skey) * 8);  // pre-swizzled source granule (elems)

  for (;;) {
    if (tid == 0) s_item = (int)atomicAdd(ctr, 1u);
    __syncthreads();  // full drain: all prior-strip VM/LDS ops retired
    const int item = s_item;
    if (item >= NITEMS) break;
    const int qt = 31 - item / NBH;     // descending cost (LPT)
    const int bh = item % NBH;
    const int b = bh / NH, h = bh - b * NH;
    const int q0 = qt * 64;
    const int nt = qt + 1;
    const int* mrow = mask + b * Tc;
    const u8* frow = flags + b * 32;

    const u16* qbase = Qh + ((size_t)bh * Tc + q0 + wave * 16 + r16) * HD;
    const short8 qf0 = *(const short8*)(qbase + g * 8);
    const short8 qf1 = *(const short8*)(qbase + 32 + g * 8);

    f32x4 acc[4];
#pragma unroll
    for (int n = 0; n < 4; ++n) acc[n] = (f32x4)(0.f);
    float mrun[4], lrun[4];
#pragma unroll
    for (int r = 0; r < 4; ++r) { mrun[r] = -3.0e38f; lrun[r] = 0.f; }

    // prologue: issue tile0 -> slot0, tile1 -> slot1 (Q loads are older; FIFO retire
    // makes the in-loop vmcnt counts conservative-correct)
#pragma unroll
    for (int p = 0; p < 2; ++p) {
      int seg = wave * 2 + p;
      int rloc = seg * 8 + skey;
      gl_lds16(Kh + ((size_t)bh * Tc + rloc) * HD + sgd, &Ks[0][seg * 512 + lane * 8]);
      gl_lds16(VT + ((size_t)bh * HD + rloc) * Tc + sgd, &Vs[0][seg * 512 + lane * 8]);
    }
    if (nt > 1) {
#pragma unroll
      for (int p = 0; p < 2; ++p) {
        int seg = wave * 2 + p;
        int rloc = seg * 8 + skey;
        gl_lds16(Kh + ((size_t)bh * Tc + 64 + rloc) * HD + sgd, &Ks[1][seg * 512 + lane * 8]);
        gl_lds16(VT + ((size_t)bh * HD + rloc) * Tc + 64 + sgd, &Vs[1][seg * 512 + lane * 8]);
      }
    }

    for (int t = 0; t < nt; ++t) {
      const int kb = t * 64;
      const int rem = nt - 1 - t;

      // ---- issue prefetch t+2 into slot (t+2)&3 (last read at iter t-2: WAR-safe) ----
      if (rem >= 2) {
        const int kb2 = kb + 128;
        const int sp = (t + 2) & 3;
#pragma unroll
        for (int p = 0; p < 2; ++p) {
          int seg = wave * 2 + p;
          int rloc = seg * 8 + skey;
          gl_lds16(Kh + ((size_t)bh * Tc + kb2 + rloc) * HD + sgd,
                   &Ks[sp][seg * 512 + lane * 8]);
          gl_lds16(VT + ((size_t)bh * HD + rloc) * Tc + kb2 + sgd,
                   &Vs[sp][seg * 512 + lane * 8]);
        }
      }

      // ---- counted wait: tile t resident for THIS wave; barrier -> for ALL waves ----
      if (rem >= 2)      asm volatile("s_waitcnt vmcnt(8)" ::: "memory");
      else if (rem == 1) asm volatile("s_waitcnt vmcnt(4)" ::: "memory");
      else               asm volatile("s_waitcnt vmcnt(0)" ::: "memory");
      __builtin_amdgcn_sched_barrier(0);
      __builtin_amdgcn_s_barrier();
      __builtin_amdgcn_sched_barrier(0);

      const u16* Kc = &Ks[t & 3][0];
      const u16* Vc = &Vs[t & 3][0];

      // ---- S = Q K^T ----
      f32x4 s[4];
#pragma unroll
      for (int n = 0; n < 4; ++n) {
        int key = n * 16 + r16;
        int k7 = key & 7;
        short8 kf0 = *(const short8*)&Kc[key * 64 + ((g ^ k7) * 8)];
        short8 kf1 = *(const short8*)&Kc[key * 64 + (((4 + g) ^ k7) * 8)];
        f32x4 z = (f32x4)(0.f);
        z = MFMA(qf0, kf0, z);
        z = MFMA(qf1, kf1, z);
        s[n] = z;
      }

      // ---- masking: skip entirely for interior all-valid tiles ----
      const bool diag = (t == nt - 1);
      if (diag || !frow[t]) {
        const int fl = frow[t];
#pragma unroll
        for (int n = 0; n < 4; ++n) {
          int keyg = kb + n * 16 + r16;
          int km = fl ? 1 : mrow[keyg];
#pragma unroll
          for (int r = 0; r < 4; ++r) {
            bool ok = (km != 0);
            if (diag) ok = ok && (keyg <= q0 + wave * 16 + g * 4 + r);
            if (!ok) s[n][r] = -3.0e38f;
          }
        }
      }

      // ---- online softmax (base-2), DPP reduces + defer-rescale ----
      float tmax[4];
#pragma unroll
      for (int r = 0; r < 4; ++r)
        tmax[r] = rowmax16(fmaxf(fmaxf(s[0][r], s[1][r]), fmaxf(s[2][r], s[3][r])));
      bool defer = (tmax[0] <= mrun[0] + 8.0f) & (tmax[1] <= mrun[1] + 8.0f) &
                   (tmax[2] <= mrun[2] + 8.0f) & (tmax[3] <= mrun[3] + 8.0f);
      if (!__all(defer)) {
#pragma unroll
        for (int r = 0; r < 4; ++r) {
          float nm = fmaxf(mrun[r], tmax[r]);
          float alpha = fexp2(mrun[r] - nm);
          mrun[r] = nm;
          lrun[r] *= alpha;
          acc[0][r] *= alpha;
          acc[1][r] *= alpha;
          acc[2][r] *= alpha;
          acc[3][r] *= alpha;
        }
      }
      float rs[4] = {0.f, 0.f, 0.f, 0.f};
#pragma unroll
      for (int n = 0; n < 4; ++n)
#pragma unroll
        for (int r = 0; r < 4; ++r) {
          float p = fexp2(s[n][r] - mrun[r]);
          s[n][r] = p;
          rs[r] += p;
        }
#pragma unroll
      for (int r = 0; r < 4; ++r) lrun[r] += rowsum16(rs[r]);

      // ---- P (bf16 via cvt_pk) -> per-wave swizzled LDS, read back as A-frags ----
      u16* pw = &Ps[wave][0];
#pragma unroll
      for (int n = 0; n < 4; ++n) {
        int key = n * 16 + r16;
        int gk = key >> 3;
        int k7 = key & 7;
        u32 p01 = cvtpk_bf16(s[n][0], s[n][1]);
        u32 p23 = cvtpk_bf16(s[n][2], s[n][3]);
        int q0l = g * 4;
        pw[(q0l + 0) * 64 + ((gk ^ ((q0l + 0) & 7)) * 8) + k7] = (u16)p01;
        pw[(q0l + 1) * 64 + ((gk ^ ((q0l + 1) & 7)) * 8) + k7] = (u16)(p01 >> 16);
        pw[(q0l + 2) * 64 + ((gk ^ ((q0l + 2) & 7)) * 8) + k7] = (u16)p23;
        pw[(q0l + 3) * 64 + ((gk ^ ((q0l + 3) & 7)) * 8) + k7] = (u16)(p23 >> 16);
      }
      asm volatile("s_waitcnt lgkmcnt(0)" ::: "memory");
      short8 pa0, pa1;
      {
        int q7 = r16 & 7;
        pa0 = *(const short8*)&pw[r16 * 64 + ((g ^ q7) * 8)];
        pa1 = *(const short8*)&pw[r16 * 64 + (((4 + g) ^ q7) * 8)];
      }

      // ---- O += P V ----
#pragma unroll
      for (int n = 0; n < 4; ++n) {
        int d = n * 16 + r16;
        int d7 = d & 7;
        short8 vf0 = *(const short8*)&Vc[d * 64 + ((g ^ d7) * 8)];
        short8 vf1 = *(const short8*)&Vc[d * 64 + (((4 + g) ^ d7) * 8)];
        acc[n] = MFMA(pa0, vf0, acc[n]);
        acc[n] = MFMA(pa1, vf1, acc[n]);
      }
      __builtin_amdgcn_sched_barrier(0);  // pin compute inside the iteration
    }

    // ---- normalize + write O[b][t][h*64+d] (bf16) ----
#pragma unroll
    for (int r = 0; r < 4; ++r) {
      int qg = q0 + wave * 16 + g * 4 + r;
      float inv = 1.0f / lrun[r];
      u16* orow = O + ((size_t)(b * Tc + qg)) * Hc + h * 64;
#pragma unroll
      for (int n = 0; n < 4; ++n) orow[n * 16 + r16] = f2bf(acc[n][r] * inv);
    }
  }
}

// ---------------- launch ----------------
extern "C" void kernel_launch(void* const* d_in, const int* in_sizes, int n_in,
                              void* d_out, int out_size, void* d_ws, size_t ws_size,
                              hipStream_t stream) {
  const float* x = (const float*)d_in[0];
  const int* mask = (const int*)d_in[1];
  const float* Wqkv = (const float*)d_in[2];
  const float* bqkv = (const float*)d_in[3];
  const float* Wproj = (const float*)d_in[4];
  const float* bproj = (const float*)d_in[5];
  float* out = (float*)d_out;

  char* ws = (char*)d_ws;
  size_t off = 0;
  auto alloc = [&](size_t bytes) {
    char* p = ws + off;
    off += (bytes + 255) & ~(size_t)255;
    return p;
  };
  u16* xb     = (u16*)alloc((size_t)BTc * Hc * 2);
  u16* WqkvT  = (u16*)alloc((size_t)N3 * Hc * 2);
  u16* WprojT = (u16*)alloc((size_t)Hc * Hc * 2);
  u16* Qh     = (u16*)alloc((size_t)BTc * Hc * 2);
  u16* Kh     = (u16*)alloc((size_t)BTc * Hc * 2);
  u16* VT     = (u16*)alloc((size_t)BTc * Hc * 2);
  u32* ctr    = (u32*)alloc(256);
  u8*  flags  = (u8*)alloc(256);
  u16* Ob     = xb;  // alias: xb dead after GEMM1, reused for attention output

  int n8 = BTc * Hc / 8;
  k_cvt<<<(n8 + 255) / 256, 256, 0, stream>>>((const float4*)x, (uint4*)xb, n8,
                                              mask, flags, ctr);
  k_transpose_w<<<dim3(N3 / 64, Hc / 64), dim3(64, 4), 0, stream>>>(Wqkv, WqkvT, Hc, N3);
  k_transpose_w<<<dim3(Hc / 64, Hc / 64), dim3(64, 4), 0, stream>>>(Wproj, WprojT, Hc, Hc);
  k_gemm<0><<<dim3(N3 / 128, BTc / 128), 256, 0, stream>>>(xb, WqkvT, bqkv, Qh, Kh, VT,
                                                           nullptr, BTc, N3, Hc);
  k_attn<<<dim3(512), 256, 0, stream>>>(Qh, Kh, VT, mask, flags, Ob, ctr);
  k_gemm<1><<<dim3(Hc / 128, BTc / 128), 256, 0, stream>>>(Ob, WprojT, bproj, nullptr,
                                                           nullptr, nullptr, out, BTc, Hc, Hc);
}

// Round 6
// 112.943 us; speedup vs baseline: 2.1520x; 1.0783x over previous
//
#include <hip/hip_runtime.h>
#include <stdint.h>

typedef unsigned short u16;
typedef unsigned int   u32;
typedef unsigned char  u8;
typedef __attribute__((ext_vector_type(8))) short short8;
typedef __attribute__((ext_vector_type(4))) float f32x4;
typedef __attribute__((ext_vector_type(4))) unsigned short u16x4;

#define DEV static __device__ __forceinline__

static constexpr int Bc = 2, Tc = 2048, Hc = 768, NH = 12, HD = 64;
static constexpr int BTc = Bc * Tc;      // 4096 rows
static constexpr int N3 = 3 * Hc;        // 2304
static constexpr int NBH = Bc * NH;      // 24
static constexpr int NITEMS = 32 * NBH;  // 768 work items (64-row q strips)
static constexpr float QSCALE = 0.125f * 1.44269504088896f; // 1/sqrt(64) * log2(e)

DEV u16 f2bf(float f) {
  u32 u = __float_as_uint(f);
  u32 r = (u + 0x7fffu + ((u >> 16) & 1u)) >> 16;  // RNE
  return (u16)r;
}

DEV float fexp2(float x) {
#if __has_builtin(__builtin_amdgcn_exp2f)
  return __builtin_amdgcn_exp2f(x);
#else
  return exp2f(x);
#endif
}

DEV u32 cvtpk_bf16(float lo, float hi) {  // packs 2 f32 -> 2 bf16 (RNE), 1 VALU op
  u32 r;
  asm("v_cvt_pk_bf16_f32 %0, %1, %2" : "=v"(r) : "v"(lo), "v"(hi));
  return r;
}

DEV void gl_lds16(const u16* g, u16* l) {
  __builtin_amdgcn_global_load_lds(
      (const __attribute__((address_space(1))) u32*)g,
      (__attribute__((address_space(3))) u32*)l, 16, 0, 0);
}

#define MFMA(a, b, c) __builtin_amdgcn_mfma_f32_16x16x32_bf16((a), (b), (c), 0, 0, 0)

// ---------------- cast x (fp32 -> bf16) + mask flags + queue counter reset ----------------
__global__ void k_cvt(const float4* __restrict__ in, uint4* __restrict__ out, int n8,
                      const int* __restrict__ mask, u8* __restrict__ flags,
                      u32* __restrict__ ctr) {
  if (blockIdx.x == 0 && threadIdx.x < 64) {
    int t = threadIdx.x;  // b = t>>5, kb = t&31
    if (t == 0) *ctr = 0;
    int b = t >> 5, kb = t & 31;
    const int* m = mask + b * Tc + kb * 64;
    int all = 1;
    for (int i = 0; i < 64; ++i) all &= (m[i] != 0);
    flags[b * 32 + kb] = (u8)all;
  }
  int i = blockIdx.x * 256 + threadIdx.x;
  if (i >= n8) return;
  float4 a = in[2 * i], b = in[2 * i + 1];
  uint4 o;
  o.x = f2bf(a.x) | ((u32)f2bf(a.y) << 16);
  o.y = f2bf(a.z) | ((u32)f2bf(a.w) << 16);
  o.z = f2bf(b.x) | ((u32)f2bf(b.y) << 16);
  o.w = f2bf(b.z) | ((u32)f2bf(b.w) << 16);
  out[i] = o;
}

// ------------- transpose + cast weights: in fp32 [R][C] -> out bf16 [C][R] -------------
__global__ __launch_bounds__(256) void k_transpose_w(const float* __restrict__ in,
                                                     u16* __restrict__ out, int R, int C) {
  __shared__ u16 tile[64][65];
  int c0 = blockIdx.x * 64, r0 = blockIdx.y * 64;
  int tx = threadIdx.x, ty = threadIdx.y;  // block (64,4)
  for (int i = ty; i < 64; i += 4)
    tile[i][tx] = f2bf(in[(size_t)(r0 + i) * C + c0 + tx]);
  __syncthreads();
  for (int i = ty; i < 64; i += 4)
    out[(size_t)(c0 + i) * R + r0 + tx] = tile[tx][i];
}

// ---------------- GEMM: C = A[M,K] * BT[N,K]^T (+bias), bf16 in, fp32 acc ----------------
// EPI=0: scatter Q(scaled)/K into [bh][t][d]; V directly TRANSPOSED into VT [bh][d][t].
// EPI=1: fp32 out + bias.
template <int EPI>
__global__ __launch_bounds__(256) void k_gemm(const u16* __restrict__ A,
                                              const u16* __restrict__ BTm,
                                              const float* __restrict__ bias,
                                              u16* __restrict__ oQ, u16* __restrict__ oK,
                                              u16* __restrict__ oV, float* __restrict__ oF,
                                              int M, int N, int K) {
  __shared__ u16 As[128 * 32];
  __shared__ u16 Bs[128 * 32];
  const int tid = threadIdx.x;
  const int lane = tid & 63, wave = tid >> 6;
  const int wr = wave >> 1, wc = wave & 1;
  const int row0 = blockIdx.y * 128, col0 = blockIdx.x * 128;

  f32x4 acc[4][4];
#pragma unroll
  for (int m = 0; m < 4; ++m)
#pragma unroll
    for (int n = 0; n < 4; ++n) acc[m][n] = (f32x4)(0.f);

  const int srow = lane >> 2;
  const int sg = lane & 3;
  const int sf = (lane >> 3) & 3;
  const int kfetch = ((sg ^ sf) * 8);

  const int r16 = lane & 15;
  const int g = lane >> 4;
  const int fr = (r16 >> 1) & 3;
  const int koff = ((g ^ fr) * 8);

  for (int k0 = 0; k0 < K; k0 += 32) {
    if (k0) __syncthreads();
#pragma unroll
    for (int p = 0; p < 2; ++p) {
      int seg = wave * 2 + p;
      int row = seg * 16 + srow;
      gl_lds16(A + (size_t)(row0 + row) * K + k0 + kfetch, &As[seg * 512 + lane * 8]);
      gl_lds16(BTm + (size_t)(col0 + row) * K + k0 + kfetch, &Bs[seg * 512 + lane * 8]);
    }
    __syncthreads();
    short8 af[4], bf[4];
#pragma unroll
    for (int m = 0; m < 4; ++m)
      af[m] = *(const short8*)&As[(wr * 64 + m * 16 + r16) * 32 + koff];
#pragma unroll
    for (int n = 0; n < 4; ++n)
      bf[n] = *(const short8*)&Bs[(wc * 64 + n * 16 + r16) * 32 + koff];
#pragma unroll
    for (int m = 0; m < 4; ++m)
#pragma unroll
      for (int n = 0; n < 4; ++n)
        acc[m][n] = MFMA(af[m], bf[n], acc[m][n]);
  }

#pragma unroll
  for (int m = 0; m < 4; ++m) {
    int rowg = row0 + wr * 64 + m * 16 + g * 4;
#pragma unroll
    for (int n = 0; n < 4; ++n) {
      int colg = col0 + wc * 64 + n * 16 + r16;
      float bv = bias[colg];
      if constexpr (EPI == 0) {
        int which = colg / Hc;
        int hc = colg - which * Hc;
        int h = hc >> 6, d = hc & 63;
        int b = rowg >> 11, t0 = rowg & 2047;  // same b for r=0..3 (128-row tiles)
        if (which == 2) {
          // V -> VT [bh][d][t], 4 consecutive t per lane -> one 8B store
          u16x4 pk;
#pragma unroll
          for (int r = 0; r < 4; ++r) pk[r] = f2bf(acc[m][n][r] + bv);
          *(u16x4*)&oV[((size_t)(b * NH + h) * HD + d) * Tc + t0] = pk;
        } else {
#pragma unroll
          for (int r = 0; r < 4; ++r) {
            float v = acc[m][n][r] + bv;
            size_t dst = ((size_t)(b * NH + h) * Tc + t0 + r) * HD + d;
            if (which == 0) oQ[dst] = f2bf(v * QSCALE);
            else            oK[dst] = f2bf(v);
          }
        }
      } else {
#pragma unroll
        for (int r = 0; r < 4; ++r)
          oF[(size_t)(rowg + r) * Hc + colg] = acc[m][n][r] + bv;
      }
    }
  }
}

// ---------------- flash attention: swapped QK^T (lane-local softmax rows) ----------------
// mfma(K,Q) -> S^T: col = q = r16, row(regs) = key = 16n+4g+r. Each lane owns q-row r16:
// mrun/lrun are per-lane scalars; exp2 path has ZERO cross-lane ops; defer check uses the
// lane-LOCAL max (if all lanes' local maxes pass, the row max passes). P-pack: cvt_pk pairs
// are k-adjacent in-lane -> 4 ds_write_b64; A-frag read offsets = same off0/off1 as K/V.
// Staging pipeline (4-slot, counted vmcnt, 1 barrier/iter) and work-stealing kept from R5.
__global__ __launch_bounds__(256) void k_attn(const u16* __restrict__ Qh,
                                              const u16* __restrict__ Kh,
                                              const u16* __restrict__ VT,
                                              const int* __restrict__ mask,
                                              const u8* __restrict__ flags,
                                              u16* __restrict__ O,
                                              u32* __restrict__ ctr) {
  __shared__ u16 Ks[4][4096];
  __shared__ u16 Vs[4][4096];
  __shared__ u16 Ps[4][1024];
  __shared__ int s_item;
  const int tid = threadIdx.x, lane = tid & 63, wave = tid >> 6;
  const int r16 = lane & 15, g = lane >> 4;
  const int r7 = r16 & 7;
  const int skey = lane >> 3;          // row within 8-row staging segment
  const int sgr = lane & 7;            // 16B granule slot
  const int sgd = ((sgr ^ skey) * 8);  // pre-swizzled source granule (elems)

  // hoisted per-lane LDS offsets (elements): row r16, granule g / 4+g, XOR-swizzled.
  // Serve K-reads (+n*1024), V-reads (+n*1024), and P A-frag reads.
  const int off0 = r16 * 64 + ((g ^ r7) * 8);
  const int off1 = r16 * 64 + (((4 + g) ^ r7) * 8);
  // P-write base (u32 units): row r16 (32 u32/row) + low-granule bit from g
  const int pwb = r16 * 32 + 2 * (g & 1);
  const int pgs = g >> 1;  // granule-select contribution

  for (;;) {
    if (tid == 0) s_item = (int)atomicAdd(ctr, 1u);
    __syncthreads();  // full drain: all prior-strip VM/LDS ops retired
    const int item = s_item;
    if (item >= NITEMS) break;
    const int qt = 31 - item / NBH;     // descending cost (LPT)
    const int bh = item % NBH;
    const int b = bh / NH, h = bh - b * NH;
    const int q0 = qt * 64;
    const int nt = qt + 1;
    const int qg = q0 + wave * 16 + r16;  // this lane's q row
    const int* mrow = mask + b * Tc;
    const u8* frow = flags + b * 32;

    const u16* qbase = Qh + ((size_t)bh * Tc + qg) * HD;
    const short8 qf0 = *(const short8*)(qbase + g * 8);
    const short8 qf1 = *(const short8*)(qbase + 32 + g * 8);

    f32x4 acc[4];
#pragma unroll
    for (int n = 0; n < 4; ++n) acc[n] = (f32x4)(0.f);
    float mrun = -3.0e38f, lrun = 0.f;  // per-lane scalars (row q = r16)

    // prologue: issue tile0 -> slot0, tile1 -> slot1
#pragma unroll
    for (int p = 0; p < 2; ++p) {
      int seg = wave * 2 + p;
      int rloc = seg * 8 + skey;
      gl_lds16(Kh + ((size_t)bh * Tc + rloc) * HD + sgd, &Ks[0][seg * 512 + lane * 8]);
      gl_lds16(VT + ((size_t)bh * HD + rloc) * Tc + sgd, &Vs[0][seg * 512 + lane * 8]);
    }
    if (nt > 1) {
#pragma unroll
      for (int p = 0; p < 2; ++p) {
        int seg = wave * 2 + p;
        int rloc = seg * 8 + skey;
        gl_lds16(Kh + ((size_t)bh * Tc + 64 + rloc) * HD + sgd, &Ks[1][seg * 512 + lane * 8]);
        gl_lds16(VT + ((size_t)bh * HD + rloc) * Tc + 64 + sgd, &Vs[1][seg * 512 + lane * 8]);
      }
    }

    for (int t = 0; t < nt; ++t) {
      const int kb = t * 64;
      const int rem = nt - 1 - t;

      // ---- issue prefetch t+2 into slot (t+2)&3 (last read at iter t-2: WAR-safe) ----
      if (rem >= 2) {
        const int kb2 = kb + 128;
        const int sp = (t + 2) & 3;
#pragma unroll
        for (int p = 0; p < 2; ++p) {
          int seg = wave * 2 + p;
          int rloc = seg * 8 + skey;
          gl_lds16(Kh + ((size_t)bh * Tc + kb2 + rloc) * HD + sgd,
                   &Ks[sp][seg * 512 + lane * 8]);
          gl_lds16(VT + ((size_t)bh * HD + rloc) * Tc + kb2 + sgd,
                   &Vs[sp][seg * 512 + lane * 8]);
        }
      }

      // ---- counted wait: tile t resident for THIS wave; barrier -> for ALL waves ----
      if (rem >= 2)      asm volatile("s_waitcnt vmcnt(8)" ::: "memory");
      else if (rem == 1) asm volatile("s_waitcnt vmcnt(4)" ::: "memory");
      else               asm volatile("s_waitcnt vmcnt(0)" ::: "memory");
      __builtin_amdgcn_sched_barrier(0);
      __builtin_amdgcn_s_barrier();
      __builtin_amdgcn_sched_barrier(0);

      const u16* Kc = &Ks[t & 3][0];
      const u16* Vc = &Vs[t & 3][0];

      // ---- S^T = K Q^T : s[n][r] = S[key = kb+16n+4g+r][q = r16] ----
      f32x4 s[4];
#pragma unroll
      for (int n = 0; n < 4; ++n) {
        short8 kf0 = *(const short8*)&Kc[n * 1024 + off0];
        short8 kf1 = *(const short8*)&Kc[n * 1024 + off1];
        f32x4 z = (f32x4)(0.f);
        z = MFMA(kf0, qf0, z);   // swapped: K is A-operand, Q is B-operand
        z = MFMA(kf1, qf1, z);
        s[n] = z;
      }

      // ---- masking: skip entirely for interior all-valid tiles ----
      const bool diag = (t == nt - 1);
      if (diag || !frow[t]) {
        const int fl = frow[t];
#pragma unroll
        for (int n = 0; n < 4; ++n)
#pragma unroll
          for (int r = 0; r < 4; ++r) {
            int keyg = kb + n * 16 + g * 4 + r;
            bool ok = fl ? true : (mrow[keyg] != 0);
            if (diag) ok = ok && (keyg <= qg);
            if (!ok) s[n][r] = -3.0e38f;
          }
      }

      // ---- online softmax: lane-local row. Local 15-fmax tree; defer on local max. ----
      float lm;
      {
        float m0 = fmaxf(fmaxf(s[0][0], s[0][1]), fmaxf(s[0][2], s[0][3]));
        float m1 = fmaxf(fmaxf(s[1][0], s[1][1]), fmaxf(s[1][2], s[1][3]));
        float m2 = fmaxf(fmaxf(s[2][0], s[2][1]), fmaxf(s[2][2], s[2][3]));
        float m3 = fmaxf(fmaxf(s[3][0], s[3][1]), fmaxf(s[3][2], s[3][3]));
        lm = fmaxf(fmaxf(m0, m1), fmaxf(m2, m3));
      }
      if (!__all(lm <= mrun + 8.0f)) {
        // true row max across the 4 g-groups, update mrun, rescale acc (rare)
        float rm = fmaxf(lm, __shfl_xor(lm, 16));
        rm = fmaxf(rm, __shfl_xor(rm, 32));
        float nm = fmaxf(mrun, rm);
        float alpha = fexp2(mrun - nm);
        mrun = nm;
        lrun *= alpha;
#pragma unroll
        for (int r = 0; r < 4; ++r) {
          float ar = __shfl(alpha, g * 4 + r);  // acc row q = 4g+r lives at lane 4g+r
          acc[0][r] *= ar;
          acc[1][r] *= ar;
          acc[2][r] *= ar;
          acc[3][r] *= ar;
        }
      }
      float rs = 0.f;
#pragma unroll
      for (int n = 0; n < 4; ++n)
#pragma unroll
        for (int r = 0; r < 4; ++r) {
          float p = fexp2(s[n][r] - mrun);
          s[n][r] = p;
          rs += p;
        }
      lrun += rs;  // per-(lane,g) partial; cross-g combine once at strip end

      // ---- P -> A-frag via 4 ds_write_b64 (k-adjacent cvt_pk pairs) ----
      u32* pw = (u32*)&Ps[wave][0];
#pragma unroll
      for (int n = 0; n < 4; ++n) {
        u32 lo = cvtpk_bf16(s[n][0], s[n][1]);  // k = 16n+4g+0,1
        u32 hi = cvtpk_bf16(s[n][2], s[n][3]);  // k = 16n+4g+2,3
        int idx = pwb + (((2 * n + pgs) ^ r7) * 4);
        *(uint2*)&pw[idx] = make_uint2(lo, hi);
      }
      asm volatile("s_waitcnt lgkmcnt(0)" ::: "memory");
      const u16* pwr = &Ps[wave][0];
      short8 pa0 = *(const short8*)&pwr[off0];  // P[q=r16][8g..8g+7]
      short8 pa1 = *(const short8*)&pwr[off1];  // P[q=r16][32+8g..]

      // ---- O += P V ----
#pragma unroll
      for (int n = 0; n < 4; ++n) {
        short8 vf0 = *(const short8*)&Vc[n * 1024 + off0];
        short8 vf1 = *(const short8*)&Vc[n * 1024 + off1];
        acc[n] = MFMA(pa0, vf0, acc[n]);
        acc[n] = MFMA(pa1, vf1, acc[n]);
      }
      __builtin_amdgcn_sched_barrier(0);  // pin compute inside the iteration
    }

    // ---- cross-g lrun combine + normalize + write O[b][t][h*64+d] (bf16) ----
    float lt = lrun + __shfl_xor(lrun, 16);
    lt += __shfl_xor(lt, 32);
#pragma unroll
    for (int r = 0; r < 4; ++r) {
      int qr = q0 + wave * 16 + g * 4 + r;
      float inv = 1.0f / __shfl(lt, g * 4 + r);
      u16* orow = O + ((size_t)(b * Tc + qr)) * Hc + h * 64;
#pragma unroll
      for (int n = 0; n < 4; ++n) orow[n * 16 + r16] = f2bf(acc[n][r] * inv);
    }
  }
}

// ---------------- launch ----------------
extern "C" void kernel_launch(void* const* d_in, const int* in_sizes, int n_in,
                              void* d_out, int out_size, void* d_ws, size_t ws_size,
                              hipStream_t stream) {
  const float* x = (const float*)d_in[0];
  const int* mask = (const int*)d_in[1];
  const float* Wqkv = (const float*)d_in[2];
  const float* bqkv = (const float*)d_in[3];
  const float* Wproj = (const float*)d_in[4];
  const float* bproj = (const float*)d_in[5];
  float* out = (float*)d_out;

  char* ws = (char*)d_ws;
  size_t off = 0;
  auto alloc = [&](size_t bytes) {
    char* p = ws + off;
    off += (bytes + 255) & ~(size_t)255;
    return p;
  };
  u16* xb     = (u16*)alloc((size_t)BTc * Hc * 2);
  u16* WqkvT  = (u16*)alloc((size_t)N3 * Hc * 2);
  u16* WprojT = (u16*)alloc((size_t)Hc * Hc * 2);
  u16* Qh     = (u16*)alloc((size_t)BTc * Hc * 2);
  u16* Kh     = (u16*)alloc((size_t)BTc * Hc * 2);
  u16* VT     = (u16*)alloc((size_t)BTc * Hc * 2);
  u32* ctr    = (u32*)alloc(256);
  u8*  flags  = (u8*)alloc(256);
  u16* Ob     = xb;  // alias: xb dead after GEMM1, reused for attention output

  int n8 = BTc * Hc / 8;
  k_cvt<<<(n8 + 255) / 256, 256, 0, stream>>>((const float4*)x, (uint4*)xb, n8,
                                              mask, flags, ctr);
  k_transpose_w<<<dim3(N3 / 64, Hc / 64), dim3(64, 4), 0, stream>>>(Wqkv, WqkvT, Hc, N3);
  k_transpose_w<<<dim3(Hc / 64, Hc / 64), dim3(64, 4), 0, stream>>>(Wproj, WprojT, Hc, Hc);
  k_gemm<0><<<dim3(N3 / 128, BTc / 128), 256, 0, stream>>>(xb, WqkvT, bqkv, Qh, Kh, VT,
                                                           nullptr, BTc, N3, Hc);
  k_attn<<<dim3(512), 256, 0, stream>>>(Qh, Kh, VT, mask, flags, Ob, ctr);
  k_gemm<1><<<dim3(Hc / 128, BTc / 128), 256, 0, stream>>>(Ob, WprojT, bproj, nullptr,
                                                           nullptr, nullptr, out, BTc, Hc, Hc);
}

// Round 7
// 107.145 us; speedup vs baseline: 2.2685x; 1.0541x over previous
//
#include <hip/hip_runtime.h>
#include <stdint.h>

typedef unsigned short u16;
typedef unsigned int   u32;
typedef unsigned char  u8;
typedef __attribute__((ext_vector_type(8))) short short8;
typedef __attribute__((ext_vector_type(4))) float f32x4;
typedef __attribute__((ext_vector_type(4))) unsigned short u16x4;

#define DEV static __device__ __forceinline__

static constexpr int Bc = 2, Tc = 2048, Hc = 768, NH = 12, HD = 64;
static constexpr int BTc = Bc * Tc;      // 4096 rows
static constexpr int N3 = 3 * Hc;        // 2304
static constexpr int NBH = Bc * NH;      // 24
static constexpr int NITEMS = 32 * NBH;  // 768 work items (64-row q strips)
static constexpr float QSCALE = 0.125f * 1.44269504088896f; // 1/sqrt(64) * log2(e)
static constexpr float MRINIT = -1.0e38f;   // mrun init
static constexpr float SMASK  = -3.0e38f;   // masked score: exp2(SMASK-MRINIT)=0

DEV u16 f2bf(float f) {
  u32 u = __float_as_uint(f);
  u32 r = (u + 0x7fffu + ((u >> 16) & 1u)) >> 16;  // RNE
  return (u16)r;
}

DEV float fexp2(float x) {
#if __has_builtin(__builtin_amdgcn_exp2f)
  return __builtin_amdgcn_exp2f(x);
#else
  return exp2f(x);
#endif
}

DEV u32 cvtpk_bf16(float lo, float hi) {  // packs 2 f32 -> 2 bf16 (RNE), 1 VALU op
  u32 r;
  asm("v_cvt_pk_bf16_f32 %0, %1, %2" : "=v"(r) : "v"(lo), "v"(hi));
  return r;
}

DEV void gl_lds16(const u16* g, u16* l) {
  __builtin_amdgcn_global_load_lds(
      (const __attribute__((address_space(1))) u32*)g,
      (__attribute__((address_space(3))) u32*)l, 16, 0, 0);
}

#define MFMA(a, b, c) __builtin_amdgcn_mfma_f32_16x16x32_bf16((a), (b), (c), 0, 0, 0)

// ---------------- cast x (fp32 -> bf16) + mask flags + queue counter reset ----------------
__global__ void k_cvt(const float4* __restrict__ in, uint4* __restrict__ out, int n8,
                      const int* __restrict__ mask, u8* __restrict__ flags,
                      u32* __restrict__ ctr) {
  if (blockIdx.x == 0 && threadIdx.x < 64) {
    int t = threadIdx.x;  // b = t>>5, kb = t&31
    if (t == 0) *ctr = 0;
    int b = t >> 5, kb = t & 31;
    const int* m = mask + b * Tc + kb * 64;
    int all = 1;
    for (int i = 0; i < 64; ++i) all &= (m[i] != 0);
    flags[b * 32 + kb] = (u8)all;
  }
  int i = blockIdx.x * 256 + threadIdx.x;
  if (i >= n8) return;
  float4 a = in[2 * i], b = in[2 * i + 1];
  uint4 o;
  o.x = f2bf(a.x) | ((u32)f2bf(a.y) << 16);
  o.y = f2bf(a.z) | ((u32)f2bf(a.w) << 16);
  o.z = f2bf(b.x) | ((u32)f2bf(b.y) << 16);
  o.w = f2bf(b.z) | ((u32)f2bf(b.w) << 16);
  out[i] = o;
}

// ------------- transpose + cast weights: in fp32 [R][C] -> out bf16 [C][R] -------------
__global__ __launch_bounds__(256) void k_transpose_w(const float* __restrict__ in,
                                                     u16* __restrict__ out, int R, int C) {
  __shared__ u16 tile[64][65];
  int c0 = blockIdx.x * 64, r0 = blockIdx.y * 64;
  int tx = threadIdx.x, ty = threadIdx.y;  // block (64,4)
  for (int i = ty; i < 64; i += 4)
    tile[i][tx] = f2bf(in[(size_t)(r0 + i) * C + c0 + tx]);
  __syncthreads();
  for (int i = ty; i < 64; i += 4)
    out[(size_t)(c0 + i) * R + r0 + tx] = tile[tx][i];
}

// ---------------- GEMM: C = A[M,K] * BT[N,K]^T (+bias), bf16 in, fp32 acc ----------------
// EPI=0: scatter Q(scaled)/K into [bh][t][d]; V directly TRANSPOSED into VT [bh][d][t].
// EPI=1: fp32 out + bias.
template <int EPI>
__global__ __launch_bounds__(256) void k_gemm(const u16* __restrict__ A,
                                              const u16* __restrict__ BTm,
                                              const float* __restrict__ bias,
                                              u16* __restrict__ oQ, u16* __restrict__ oK,
                                              u16* __restrict__ oV, float* __restrict__ oF,
                                              int M, int N, int K) {
  __shared__ u16 As[128 * 32];
  __shared__ u16 Bs[128 * 32];
  const int tid = threadIdx.x;
  const int lane = tid & 63, wave = tid >> 6;
  const int wr = wave >> 1, wc = wave & 1;
  const int row0 = blockIdx.y * 128, col0 = blockIdx.x * 128;

  f32x4 acc[4][4];
#pragma unroll
  for (int m = 0; m < 4; ++m)
#pragma unroll
    for (int n = 0; n < 4; ++n) acc[m][n] = (f32x4)(0.f);

  const int srow = lane >> 2;
  const int sg = lane & 3;
  const int sf = (lane >> 3) & 3;
  const int kfetch = ((sg ^ sf) * 8);

  const int r16 = lane & 15;
  const int g = lane >> 4;
  const int fr = (r16 >> 1) & 3;
  const int koff = ((g ^ fr) * 8);

  for (int k0 = 0; k0 < K; k0 += 32) {
    if (k0) __syncthreads();
#pragma unroll
    for (int p = 0; p < 2; ++p) {
      int seg = wave * 2 + p;
      int row = seg * 16 + srow;
      gl_lds16(A + (size_t)(row0 + row) * K + k0 + kfetch, &As[seg * 512 + lane * 8]);
      gl_lds16(BTm + (size_t)(col0 + row) * K + k0 + kfetch, &Bs[seg * 512 + lane * 8]);
    }
    __syncthreads();
    short8 af[4], bf[4];
#pragma unroll
    for (int m = 0; m < 4; ++m)
      af[m] = *(const short8*)&As[(wr * 64 + m * 16 + r16) * 32 + koff];
#pragma unroll
    for (int n = 0; n < 4; ++n)
      bf[n] = *(const short8*)&Bs[(wc * 64 + n * 16 + r16) * 32 + koff];
#pragma unroll
    for (int m = 0; m < 4; ++m)
#pragma unroll
      for (int n = 0; n < 4; ++n)
        acc[m][n] = MFMA(af[m], bf[n], acc[m][n]);
  }

#pragma unroll
  for (int m = 0; m < 4; ++m) {
    int rowg = row0 + wr * 64 + m * 16 + g * 4;
#pragma unroll
    for (int n = 0; n < 4; ++n) {
      int colg = col0 + wc * 64 + n * 16 + r16;
      float bv = bias[colg];
      if constexpr (EPI == 0) {
        int which = colg / Hc;
        int hc = colg - which * Hc;
        int h = hc >> 6, d = hc & 63;
        int b = rowg >> 11, t0 = rowg & 2047;  // same b for r=0..3 (128-row tiles)
        if (which == 2) {
          // V -> VT [bh][d][t], 4 consecutive t per lane -> one 8B store
          u16x4 pk;
#pragma unroll
          for (int r = 0; r < 4; ++r) pk[r] = f2bf(acc[m][n][r] + bv);
          *(u16x4*)&oV[((size_t)(b * NH + h) * HD + d) * Tc + t0] = pk;
        } else {
#pragma unroll
          for (int r = 0; r < 4; ++r) {
            float v = acc[m][n][r] + bv;
            size_t dst = ((size_t)(b * NH + h) * Tc + t0 + r) * HD + d;
            if (which == 0) oQ[dst] = f2bf(v * QSCALE);
            else            oK[dst] = f2bf(v);
          }
        }
      } else {
#pragma unroll
        for (int r = 0; r < 4; ++r)
          oF[(size_t)(rowg + r) * Hc + colg] = acc[m][n][r] + bv;
      }
    }
  }
}

// ---------------- flash attention: 8 waves = 4 q-groups x 2 key-halves ----------------
// Wave w: q-rows [q0 + 16*(w>>1), +16), keys 32*(w&1)..+31 of each 64-key tile.
// Each wave runs an INDEPENDENT online softmax over its key subset (valid flash
// partial); pairs merge once per strip via (m,l,O) through dead K-slot LDS.
// Staging: 4-slot ring, counted vmcnt (2 gl_lds/tile/wave -> 4/2/0), 1 barrier/iter.
// Work-stealing queue (768 items desc) + grid 512 kept from R5/R6.
__global__ __launch_bounds__(512, 4) void k_attn(const u16* __restrict__ Qh,
                                                 const u16* __restrict__ Kh,
                                                 const u16* __restrict__ VT,
                                                 const int* __restrict__ mask,
                                                 const u8* __restrict__ flags,
                                                 u16* __restrict__ O,
                                                 u32* __restrict__ ctr) {
  __shared__ u16 Ks[4][4096];
  __shared__ u16 Vs[4][4096];
  __shared__ u16 Ps[8][512];   // per-wave P (16q x 32k bf16); ml region aliases Ps[0] at strip end
  __shared__ int s_item;
  const int tid = threadIdx.x, lane = tid & 63, wave = tid >> 6;  // 0..7
  const int qgrp = wave >> 1;          // q-group 0..3
  const int kh = wave & 1;             // key half
  const int r16 = lane & 15, g = lane >> 4;
  const int r7 = r16 & 7;
  const int skey = lane >> 3;          // row within 8-row staging segment
  const int sgr = lane & 7;            // 16B granule slot
  const int sgd = ((sgr ^ skey) * 8);  // pre-swizzled source granule (elems)

  // K/V fragment offsets (elements), XOR-swizzled; +n*1024 selects the 16-row group.
  const int off0 = r16 * 64 + ((g ^ r7) * 8);          // d/key granule g
  const int off1 = r16 * 64 + (((4 + g) ^ r7) * 8);    // granule 4+g
  const int offv = kh ? off1 : off0;                   // V^T frag for this wave's keys
  // P LDS (u32 units within Ps[wave]): row r16 = q (16 u32), granule XOR (r16&3).
  const int prd = r16 * 16 + ((g ^ (r16 & 3)) << 2);   // b128 read: keys 8g..8g+7

  for (;;) {
    if (tid == 0) s_item = (int)atomicAdd(ctr, 1u);
    __syncthreads();
    const int item = s_item;
    if (item >= NITEMS) break;
    const int qt = 31 - item / NBH;     // descending cost (LPT)
    const int bh = item % NBH;
    const int b = bh / NH, h = bh - b * NH;
    const int q0 = qt * 64;
    const int nt = qt + 1;
    const int qg = q0 + qgrp * 16 + r16;  // this lane's q row
    const int* mrow = mask + b * Tc;
    const u8* frow = flags + b * 32;

    const u16* qbase = Qh + ((size_t)bh * Tc + qg) * HD;
    const short8 qf0 = *(const short8*)(qbase + g * 8);
    const short8 qf1 = *(const short8*)(qbase + 32 + g * 8);

    f32x4 acc[4];
#pragma unroll
    for (int n = 0; n < 4; ++n) acc[n] = (f32x4)(0.f);
    float mrun = MRINIT, lrun = 0.f;

    // prologue: stage tile0 -> slot0, tile1 -> slot1 (1 K-seg + 1 V-seg per wave)
    {
      int rloc = wave * 8 + skey;
      gl_lds16(Kh + ((size_t)bh * Tc + rloc) * HD + sgd, &Ks[0][wave * 512 + lane * 8]);
      gl_lds16(VT + ((size_t)bh * HD + rloc) * Tc + sgd, &Vs[0][wave * 512 + lane * 8]);
      if (nt > 1) {
        gl_lds16(Kh + ((size_t)bh * Tc + 64 + rloc) * HD + sgd, &Ks[1][wave * 512 + lane * 8]);
        gl_lds16(VT + ((size_t)bh * HD + rloc) * Tc + 64 + sgd, &Vs[1][wave * 512 + lane * 8]);
      }
    }

    for (int t = 0; t < nt; ++t) {
      const int kb = t * 64;
      const int rem = nt - 1 - t;

      // ---- issue prefetch t+2 into slot (t+2)&3 (readers at t-2: WAR-safe) ----
      if (rem >= 2) {
        const int kb2 = kb + 128;
        const int sp = (t + 2) & 3;
        int rloc = wave * 8 + skey;
        gl_lds16(Kh + ((size_t)bh * Tc + kb2 + rloc) * HD + sgd,
                 &Ks[sp][wave * 512 + lane * 8]);
        gl_lds16(VT + ((size_t)bh * HD + rloc) * Tc + kb2 + sgd,
                 &Vs[sp][wave * 512 + lane * 8]);
      }

      // ---- counted wait (own loads), then barrier (cross-wave residency) ----
      if (rem >= 2)      asm volatile("s_waitcnt vmcnt(4)" ::: "memory");
      else if (rem == 1) asm volatile("s_waitcnt vmcnt(2)" ::: "memory");
      else               asm volatile("s_waitcnt vmcnt(0)" ::: "memory");
      __builtin_amdgcn_sched_barrier(0);
      __builtin_amdgcn_s_barrier();
      __builtin_amdgcn_sched_barrier(0);

      const u16* Kc = &Ks[t & 3][0];
      const u16* Vc = &Vs[t & 3][0];

      // ---- S^T = K Q^T for this wave's 2 key-16-groups (ng = 2*kh + n') ----
      f32x4 s[2];
      __builtin_amdgcn_s_setprio(1);
#pragma unroll
      for (int np = 0; np < 2; ++np) {
        const int ng = 2 * kh + np;
        short8 kf0 = *(const short8*)&Kc[ng * 1024 + off0];
        short8 kf1 = *(const short8*)&Kc[ng * 1024 + off1];
        f32x4 z = (f32x4)(0.f);
        z = MFMA(kf0, qf0, z);
        z = MFMA(kf1, qf1, z);
        s[np] = z;
      }
      __builtin_amdgcn_s_setprio(0);

      // ---- masking (interior all-valid tiles skip) ----
      const bool diag = (t == nt - 1);
      if (diag || !frow[t]) {
        const int fl = frow[t];
#pragma unroll
        for (int np = 0; np < 2; ++np)
#pragma unroll
          for (int r = 0; r < 4; ++r) {
            int keyg = kb + 16 * (2 * kh + np) + 4 * g + r;
            bool ok = fl ? true : (mrow[keyg] != 0);
            if (diag) ok = ok && (keyg <= qg);
            if (!ok) s[np][r] = SMASK;
          }
      }

      // ---- online softmax over this wave's 32 keys (lane-local row q=r16) ----
      float lm;
      {
        float m0 = fmaxf(fmaxf(s[0][0], s[0][1]), fmaxf(s[0][2], s[0][3]));
        float m1 = fmaxf(fmaxf(s[1][0], s[1][1]), fmaxf(s[1][2], s[1][3]));
        lm = fmaxf(m0, m1);
      }
      if (!__all(lm <= mrun + 8.0f)) {
        float rm = fmaxf(lm, __shfl_xor(lm, 16));
        rm = fmaxf(rm, __shfl_xor(rm, 32));
        float nm = fmaxf(mrun, rm);
        float alpha = fexp2(mrun - nm);
        mrun = nm;
        lrun *= alpha;
#pragma unroll
        for (int r = 0; r < 4; ++r) {
          float ar = __shfl(alpha, g * 4 + r);  // acc row q=4g+r lives at lane 4g+r
          acc[0][r] *= ar;
          acc[1][r] *= ar;
          acc[2][r] *= ar;
          acc[3][r] *= ar;
        }
      }
      float rs = 0.f;
#pragma unroll
      for (int np = 0; np < 2; ++np)
#pragma unroll
        for (int r = 0; r < 4; ++r) {
          float p = fexp2(s[np][r] - mrun);
          s[np][r] = p;
          rs += p;
        }
      lrun += rs;  // partial per (q=r16, g); cross-g combine at strip end

      // ---- P -> per-wave LDS (2x ds_write_b64), read back one b128 A-frag ----
      u32* pw = (u32*)&Ps[wave][0];
#pragma unroll
      for (int np = 0; np < 2; ++np) {
        u32 lo = cvtpk_bf16(s[np][0], s[np][1]);
        u32 hi = cvtpk_bf16(s[np][2], s[np][3]);
        int kg = 2 * np + (g >> 1);                       // key granule (8 keys)
        int idx = r16 * 16 + ((kg ^ (r16 & 3)) << 2) + 2 * (g & 1);
        *(uint2*)&pw[idx] = make_uint2(lo, hi);
      }
      short8 pa = *(const short8*)&pw[prd];  // P[q=r16][keys kh*32 is implicit: local 8g..8g+7]

      // ---- O-partial += P V (4 d-tiles, one K=32 MFMA each) ----
      __builtin_amdgcn_s_setprio(1);
#pragma unroll
      for (int n = 0; n < 4; ++n) {
        short8 vf = *(const short8*)&Vc[n * 1024 + offv];
        acc[n] = MFMA(pa, vf, acc[n]);
      }
      __builtin_amdgcn_s_setprio(0);
      __builtin_amdgcn_sched_barrier(0);
    }

    // ---- strip end: cross-g l combine, pairwise (m,l,O) merge, store ----
    float lt = lrun + __shfl_xor(lrun, 16);
    lt += __shfl_xor(lt, 32);              // full per-q sum (valid in all lanes)

    __syncthreads();  // all waves done with K/V slots (frees Ks for merge buffers)
    float* ab = (float*)&Ks[0][0] + qgrp * 1024;  // [16 q][64 d] f32 per pair (16KB tot)
    float* ml = (float*)&Ps[0][0];                // [pair][16 q][m,l] (512B)
    if (kh == 1) {
#pragma unroll
      for (int n = 0; n < 4; ++n)
#pragma unroll
        for (int r = 0; r < 4; ++r)
          ab[(4 * g + r) * 64 + 16 * n + r16] = acc[n][r];
      if (g == 0) {
        ml[qgrp * 32 + r16 * 2]     = mrun;
        ml[qgrp * 32 + r16 * 2 + 1] = lt;
      }
    }
    __syncthreads();
    if (kh == 0) {
#pragma unroll
      for (int r = 0; r < 4; ++r) {
        int q = 4 * g + r;
        float mA = __shfl(mrun, q);
        float lA = __shfl(lt, q);
        float mB = ml[qgrp * 32 + q * 2];
        float lB = ml[qgrp * 32 + q * 2 + 1];
        float ms = fmaxf(mA, mB);
        float cA = fexp2(mA - ms);
        float cB = fexp2(mB - ms);
        float linv = 1.0f / (lA * cA + lB * cB);
        int qr = q0 + qgrp * 16 + q;
        u16* orow = O + ((size_t)(b * Tc + qr)) * Hc + h * 64;
#pragma unroll
        for (int n = 0; n < 4; ++n) {
          float v = (acc[n][r] * cA + ab[q * 64 + 16 * n + r16] * cB) * linv;
          orow[n * 16 + r16] = f2bf(v);
        }
      }
    }
    // loop-top __syncthreads orders merge reads before next strip's staging writes
  }
}

// ---------------- launch ----------------
extern "C" void kernel_launch(void* const* d_in, const int* in_sizes, int n_in,
                              void* d_out, int out_size, void* d_ws, size_t ws_size,
                              hipStream_t stream) {
  const float* x = (const float*)d_in[0];
  const int* mask = (const int*)d_in[1];
  const float* Wqkv = (const float*)d_in[2];
  const float* bqkv = (const float*)d_in[3];
  const float* Wproj = (const float*)d_in[4];
  const float* bproj = (const float*)d_in[5];
  float* out = (float*)d_out;

  char* ws = (char*)d_ws;
  size_t off = 0;
  auto alloc = [&](size_t bytes) {
    char* p = ws + off;
    off += (bytes + 255) & ~(size_t)255;
    return p;
  };
  u16* xb     = (u16*)alloc((size_t)BTc * Hc * 2);
  u16* WqkvT  = (u16*)alloc((size_t)N3 * Hc * 2);
  u16* WprojT = (u16*)alloc((size_t)Hc * Hc * 2);
  u16* Qh     = (u16*)alloc((size_t)BTc * Hc * 2);
  u16* Kh     = (u16*)alloc((size_t)BTc * Hc * 2);
  u16* VT     = (u16*)alloc((size_t)BTc * Hc * 2);
  u32* ctr    = (u32*)alloc(256);
  u8*  flags  = (u8*)alloc(256);
  u16* Ob     = xb;  // alias: xb dead after GEMM1, reused for attention output

  int n8 = BTc * Hc / 8;
  k_cvt<<<(n8 + 255) / 256, 256, 0, stream>>>((const float4*)x, (uint4*)xb, n8,
                                              mask, flags, ctr);
  k_transpose_w<<<dim3(N3 / 64, Hc / 64), dim3(64, 4), 0, stream>>>(Wqkv, WqkvT, Hc, N3);
  k_transpose_w<<<dim3(Hc / 64, Hc / 64), dim3(64, 4), 0, stream>>>(Wproj, WprojT, Hc, Hc);
  k_gemm<0><<<dim3(N3 / 128, BTc / 128), 256, 0, stream>>>(xb, WqkvT, bqkv, Qh, Kh, VT,
                                                           nullptr, BTc, N3, Hc);
  k_attn<<<dim3(512), 512, 0, stream>>>(Qh, Kh, VT, mask, flags, Ob, ctr);
  k_gemm<1><<<dim3(Hc / 128, BTc / 128), 256, 0, stream>>>(Ob, WprojT, bproj, nullptr,
                                                           nullptr, nullptr, out, BTc, Hc, Hc);
}

// Round 8
// 100.338 us; speedup vs baseline: 2.4224x; 1.0678x over previous
//
#include <hip/hip_runtime.h>
#include <stdint.h>

typedef unsigned short u16;
typedef unsigned int   u32;
typedef unsigned char  u8;
typedef __attribute__((ext_vector_type(8))) short short8;
typedef __attribute__((ext_vector_type(4))) float f32x4;
typedef __attribute__((ext_vector_type(4))) unsigned short u16x4;

#define DEV static __device__ __forceinline__

static constexpr int Bc = 2, Tc = 2048, Hc = 768, NH = 12, HD = 64;
static constexpr int BTc = Bc * Tc;      // 4096 rows
static constexpr int N3 = 3 * Hc;        // 2304
static constexpr int NBH = Bc * NH;      // 24
static constexpr int NITEMS = 32 * NBH;  // 768 work items (64-row q strips)
static constexpr float QSCALE = 0.125f * 1.44269504088896f; // 1/sqrt(64) * log2(e)
static constexpr float MRINIT = -1.0e38f;   // mrun init
static constexpr float SMASK  = -3.0e38f;   // masked score: exp2(SMASK-MRINIT)=0

DEV u16 f2bf(float f) {
  u32 u = __float_as_uint(f);
  u32 r = (u + 0x7fffu + ((u >> 16) & 1u)) >> 16;  // RNE
  return (u16)r;
}

DEV float fexp2(float x) {
#if __has_builtin(__builtin_amdgcn_exp2f)
  return __builtin_amdgcn_exp2f(x);
#else
  return exp2f(x);
#endif
}

DEV u32 cvtpk_bf16(float lo, float hi) {  // packs 2 f32 -> 2 bf16 (RNE); lo in bits[15:0]
  u32 r;
  asm("v_cvt_pk_bf16_f32 %0, %1, %2" : "=v"(r) : "v"(lo), "v"(hi));
  return r;
}

DEV void gl_lds16(const u16* g, u16* l) {
  __builtin_amdgcn_global_load_lds(
      (const __attribute__((address_space(1))) u32*)g,
      (__attribute__((address_space(3))) u32*)l, 16, 0, 0);
}

#define MFMA(a, b, c) __builtin_amdgcn_mfma_f32_16x16x32_bf16((a), (b), (c), 0, 0, 0)

// ---------------- cast x (fp32 -> bf16) + mask flags + queue counter reset ----------------
__global__ void k_cvt(const float4* __restrict__ in, uint4* __restrict__ out, int n8,
                      const int* __restrict__ mask, u8* __restrict__ flags,
                      u32* __restrict__ ctr) {
  if (blockIdx.x == 0 && threadIdx.x < 64) {
    int t = threadIdx.x;  // b = t>>5, kb = t&31
    if (t == 0) *ctr = 0;
    int b = t >> 5, kb = t & 31;
    const int* m = mask + b * Tc + kb * 64;
    int all = 1;
    for (int i = 0; i < 64; ++i) all &= (m[i] != 0);
    flags[b * 32 + kb] = (u8)all;
  }
  int i = blockIdx.x * 256 + threadIdx.x;
  if (i >= n8) return;
  float4 a = in[2 * i], b = in[2 * i + 1];
  uint4 o;
  o.x = f2bf(a.x) | ((u32)f2bf(a.y) << 16);
  o.y = f2bf(a.z) | ((u32)f2bf(a.w) << 16);
  o.z = f2bf(b.x) | ((u32)f2bf(b.y) << 16);
  o.w = f2bf(b.z) | ((u32)f2bf(b.w) << 16);
  out[i] = o;
}

// ------- transpose + cast BOTH weights in one launch: fp32 [R][C] -> bf16 [C][R] -------
__global__ __launch_bounds__(256) void k_transpose_w2(const float* __restrict__ Wqkv,
                                                      const float* __restrict__ Wproj,
                                                      u16* __restrict__ WqkvT,
                                                      u16* __restrict__ WprojT) {
  __shared__ u16 tile[64][65];
  int y = blockIdx.y, x = blockIdx.x;
  const float* in; u16* out; int R, C, r0, c0;
  if (y < 12) { in = Wqkv; out = WqkvT; R = Hc; C = N3; r0 = y * 64; c0 = x * 64; }
  else {
    if (x >= 12) return;
    in = Wproj; out = WprojT; R = Hc; C = Hc; r0 = (y - 12) * 64; c0 = x * 64;
  }
  int tx = threadIdx.x, ty = threadIdx.y;  // block (64,4)
  for (int i = ty; i < 64; i += 4)
    tile[i][tx] = f2bf(in[(size_t)(r0 + i) * C + c0 + tx]);
  __syncthreads();
  for (int i = ty; i < 64; i += 4)
    out[(size_t)(c0 + i) * R + r0 + tx] = tile[tx][i];
}

// ---------------- GEMM: C = A[M,K] * BT[N,K]^T (+bias), bf16 in, fp32 acc ----------------
// EPI=0: scatter Q(scaled)/K into [bh][t][d]; V directly TRANSPOSED into VT [bh][d][t].
// EPI=1: fp32 out + bias.
template <int EPI>
__global__ __launch_bounds__(256) void k_gemm(const u16* __restrict__ A,
                                              const u16* __restrict__ BTm,
                                              const float* __restrict__ bias,
                                              u16* __restrict__ oQ, u16* __restrict__ oK,
                                              u16* __restrict__ oV, float* __restrict__ oF,
                                              int M, int N, int K) {
  __shared__ u16 As[128 * 32];
  __shared__ u16 Bs[128 * 32];
  const int tid = threadIdx.x;
  const int lane = tid & 63, wave = tid >> 6;
  const int wr = wave >> 1, wc = wave & 1;
  const int row0 = blockIdx.y * 128, col0 = blockIdx.x * 128;

  f32x4 acc[4][4];
#pragma unroll
  for (int m = 0; m < 4; ++m)
#pragma unroll
    for (int n = 0; n < 4; ++n) acc[m][n] = (f32x4)(0.f);

  const int srow = lane >> 2;
  const int sg = lane & 3;
  const int sf = (lane >> 3) & 3;
  const int kfetch = ((sg ^ sf) * 8);

  const int r16 = lane & 15;
  const int g = lane >> 4;
  const int fr = (r16 >> 1) & 3;
  const int koff = ((g ^ fr) * 8);

  for (int k0 = 0; k0 < K; k0 += 32) {
    if (k0) __syncthreads();
#pragma unroll
    for (int p = 0; p < 2; ++p) {
      int seg = wave * 2 + p;
      int row = seg * 16 + srow;
      gl_lds16(A + (size_t)(row0 + row) * K + k0 + kfetch, &As[seg * 512 + lane * 8]);
      gl_lds16(BTm + (size_t)(col0 + row) * K + k0 + kfetch, &Bs[seg * 512 + lane * 8]);
    }
    __syncthreads();
    short8 af[4], bf[4];
#pragma unroll
    for (int m = 0; m < 4; ++m)
      af[m] = *(const short8*)&As[(wr * 64 + m * 16 + r16) * 32 + koff];
#pragma unroll
    for (int n = 0; n < 4; ++n)
      bf[n] = *(const short8*)&Bs[(wc * 64 + n * 16 + r16) * 32 + koff];
#pragma unroll
    for (int m = 0; m < 4; ++m)
#pragma unroll
      for (int n = 0; n < 4; ++n)
        acc[m][n] = MFMA(af[m], bf[n], acc[m][n]);
  }

#pragma unroll
  for (int m = 0; m < 4; ++m) {
    int rowg = row0 + wr * 64 + m * 16 + g * 4;
#pragma unroll
    for (int n = 0; n < 4; ++n) {
      int colg = col0 + wc * 64 + n * 16 + r16;
      float bv = bias[colg];
      if constexpr (EPI == 0) {
        int which = colg / Hc;
        int hc = colg - which * Hc;
        int h = hc >> 6, d = hc & 63;
        int b = rowg >> 11, t0 = rowg & 2047;  // same b for r=0..3 (128-row tiles)
        if (which == 2) {
          // V -> VT [bh][d][t], 4 consecutive t per lane -> one 8B store
          u16x4 pk;
#pragma unroll
          for (int r = 0; r < 4; ++r) pk[r] = f2bf(acc[m][n][r] + bv);
          *(u16x4*)&oV[((size_t)(b * NH + h) * HD + d) * Tc + t0] = pk;
        } else {
#pragma unroll
          for (int r = 0; r < 4; ++r) {
            float v = acc[m][n][r] + bv;
            size_t dst = ((size_t)(b * NH + h) * Tc + t0 + r) * HD + d;
            if (which == 0) oQ[dst] = f2bf(v * QSCALE);
            else            oK[dst] = f2bf(v);
          }
        }
      } else {
#pragma unroll
        for (int r = 0; r < 4; ++r)
          oF[(size_t)(rowg + r) * Hc + colg] = acc[m][n][r] + bv;
      }
    }
  }
}

// ---------------- flash attention: KVBLK=128, 8 waves = 4 q-groups x 2 key-halves ----------------
// Wave w: q-rows [q0+16*(w>>1), +16), keys 64*(w&1)..+63 of each 128-key tile (independent
// online-softmax partial; pairwise merge per strip). Iterations HALVED vs R7: per iter
// 8 QK-MFMA + 8 PV-MFMA per wave. 2-slot dbuf; issue t+1 AFTER iter-t barrier (slot last
// read at t-1 -> WAR-safe); own-loads vmcnt(0) at iter top (a full compute phase after issue).
// LDS exactly 80KB -> 2 blocks/CU. s_item aliased into Ps[1], merge ml into Ps[0].
__global__ __launch_bounds__(512, 4) void k_attn(const u16* __restrict__ Qh,
                                                 const u16* __restrict__ Kh,
                                                 const u16* __restrict__ VT,
                                                 const int* __restrict__ mask,
                                                 const u8* __restrict__ flags,
                                                 u16* __restrict__ O,
                                                 u32* __restrict__ ctr) {
  __shared__ u16 Ks[2][8192];   // [slot][key:128][d:64] swizzled
  __shared__ u16 Vs[2][8192];   // [slot][d:64][t:128] swizzled
  __shared__ u16 Ps[8][1024];   // per-wave P: [q:16][pair:32] u32 (2KB each)
  int* s_item = (int*)&Ps[1][0];    // aliased: consumed right after loop-top sync,
                                    // before any wave-1 P write of the new strip
  float* ml = (float*)&Ps[0][0];    // strip-end merge scalars (wave0 P region, dead then)
  const int tid = threadIdx.x, lane = tid & 63, wave = tid >> 6;  // 0..7
  const int qgrp = wave >> 1;          // q-group 0..3
  const int kh = wave & 1;             // key half (64 keys)
  const int r16 = lane & 15, g = lane >> 4;
  const int r7 = r16 & 7;
  const int skey = lane >> 3;          // K staging: row within 8-row segment
  const int sgr = lane & 7;            // K staging: 16B granule slot
  const int sgd = ((sgr ^ skey) * 8);  // K pre-swizzled source granule (elems)

  // K frag offsets (u16), row r16, XOR-swizzled; +ng*1024 selects key-16-group ng(0..7).
  const int off0 = r16 * 64 + ((g ^ r7) * 8);
  const int off1 = r16 * 64 + (((4 + g) ^ r7) * 8);
  // V frag offsets (u16): row d = 16n + r16 (stride 128), key-granule in wave's half.
  const int vo0 = r16 * 128 + (kh * 8 + (g ^ r7)) * 8;
  const int vo1 = r16 * 128 + (kh * 8 + ((4 + g) ^ r7)) * 8;
  // V staging: lane covers d-row (lane>>4) within 4-row group, t-granule r16.
  // P A-frag reads use off0/off1 (identical layout math; 32 u32 = 64 u16 per q-row).

  for (;;) {
    if (tid == 0) *s_item = (int)atomicAdd(ctr, 1u);
    __syncthreads();
    const int item = *s_item;
    if (item >= NITEMS) break;
    const int qt = 31 - item / NBH;     // descending cost (LPT)
    const int bh = item % NBH;
    const int b = bh / NH, h = bh - b * NH;
    const int q0 = qt * 64;
    const int nt = qt / 2 + 1;          // 128-key tiles
    const int qg = q0 + qgrp * 16 + r16;  // this lane's q row
    const int* mrow = mask + b * Tc;
    const u8* frow = flags + b * 32;

    const u16* qbase = Qh + ((size_t)bh * Tc + qg) * HD;
    const short8 qf0 = *(const short8*)(qbase + g * 8);
    const short8 qf1 = *(const short8*)(qbase + 32 + g * 8);

    f32x4 acc[4];
#pragma unroll
    for (int n = 0; n < 4; ++n) acc[n] = (f32x4)(0.f);
    float mrun = MRINIT, lrun = 0.f;

    // ---- staging macro-equivalent: 2 K ops (16 key rows) + 2 V ops (8 d rows) per wave ----
    auto stage = [&](int slot, int kb) {
#pragma unroll
      for (int p = 0; p < 2; ++p) {
        int seg = 2 * wave + p;
        int rloc = 8 * seg + skey;  // key row 0..127
        gl_lds16(Kh + ((size_t)bh * Tc + kb + rloc) * HD + sgd,
                 &Ks[slot][seg * 512 + lane * 8]);
      }
#pragma unroll
      for (int p = 0; p < 2; ++p) {
        int dloc = 8 * wave + 4 * p + g;  // d row 0..63
        int vsg = (((r16 & 8) | ((r16 & 7) ^ (dloc & 7)))) * 8;  // pre-swizzled t-granule
        gl_lds16(VT + ((size_t)bh * HD + dloc) * Tc + kb + vsg,
                 &Vs[slot][wave * 1024 + p * 512 + lane * 8]);
      }
    };

    stage(0, 0);  // prologue: tile 0 -> slot 0

    for (int t = 0; t < nt; ++t) {
      const int kb = t * 128;

      // own tile-t loads resident (issued one full iteration ago), then cross-wave barrier
      asm volatile("s_waitcnt vmcnt(0)" ::: "memory");
      __builtin_amdgcn_sched_barrier(0);
      __builtin_amdgcn_s_barrier();
      __builtin_amdgcn_sched_barrier(0);

      // issue next tile into the other slot (last read at t-1; barrier makes WAR safe)
      if (t + 1 < nt) stage((t + 1) & 1, kb + 128);

      const u16* Kc = &Ks[t & 1][0];
      const u16* Vc = &Vs[t & 1][0];

      const int kbw = kb + 64 * kh;              // this wave's key base
      const bool dead = (kbw > q0 + 63);         // fully-masked half (even-qt last tile)
      if (!dead) {
        // ---- S^T = K Q^T : s[nn][r] = S[key = kbw+16nn+4g+r][q = r16] ----
        f32x4 s[4];
        __builtin_amdgcn_s_setprio(1);
#pragma unroll
        for (int nn = 0; nn < 4; ++nn) {
          const int ng = 4 * kh + nn;
          short8 kf0 = *(const short8*)&Kc[ng * 1024 + off0];
          short8 kf1 = *(const short8*)&Kc[ng * 1024 + off1];
          f32x4 z = (f32x4)(0.f);
          z = MFMA(kf0, qf0, z);
          z = MFMA(kf1, qf1, z);
          s[nn] = z;
        }
        __builtin_amdgcn_s_setprio(0);

        // ---- masking (interior all-valid subtiles skip; flags indexed by 64-key subtile) ----
        const bool diag = (kbw == q0);
        if (diag || !frow[2 * t + kh]) {
          const int fl = frow[2 * t + kh];
#pragma unroll
          for (int nn = 0; nn < 4; ++nn)
#pragma unroll
            for (int r = 0; r < 4; ++r) {
              int keyg = kbw + 16 * nn + 4 * g + r;
              bool ok = fl ? true : (mrow[keyg] != 0);
              if (diag) ok = ok && (keyg <= qg);
              if (!ok) s[nn][r] = SMASK;
            }
        }

        // ---- online softmax over this wave's 64 keys (lane-local row q=r16) ----
        float lm;
        {
          float m0 = fmaxf(fmaxf(s[0][0], s[0][1]), fmaxf(s[0][2], s[0][3]));
          float m1 = fmaxf(fmaxf(s[1][0], s[1][1]), fmaxf(s[1][2], s[1][3]));
          float m2 = fmaxf(fmaxf(s[2][0], s[2][1]), fmaxf(s[2][2], s[2][3]));
          float m3 = fmaxf(fmaxf(s[3][0], s[3][1]), fmaxf(s[3][2], s[3][3]));
          lm = fmaxf(fmaxf(m0, m1), fmaxf(m2, m3));
        }
        if (!__all(lm <= mrun + 8.0f)) {
          float rm = fmaxf(lm, __shfl_xor(lm, 16));
          rm = fmaxf(rm, __shfl_xor(rm, 32));
          float nm = fmaxf(mrun, rm);
          float alpha = fexp2(mrun - nm);
          mrun = nm;
          lrun *= alpha;
#pragma unroll
          for (int r = 0; r < 4; ++r) {
            float ar = __shfl(alpha, g * 4 + r);  // acc row q=4g+r lives at lane 4g+r
            acc[0][r] *= ar;
            acc[1][r] *= ar;
            acc[2][r] *= ar;
            acc[3][r] *= ar;
          }
        }
        float rs = 0.f;
#pragma unroll
        for (int nn = 0; nn < 4; ++nn)
#pragma unroll
          for (int r = 0; r < 4; ++r) {
            float p = fexp2(s[nn][r] - mrun);
            s[nn][r] = p;
            rs += p;
          }
        lrun += rs;  // partial per (q=r16, g); cross-g combine at strip end

        // ---- P -> per-wave LDS (4x ds_write_b64), read back 2 b128 A-frags ----
        // pair p = 8nn + 2g + rr <-> keys kbw + 16nn+4g+2rr,+1; row q=r16 (32 u32),
        // granule (4 u32) XOR-swizzled by r7.
        u32* pw = (u32*)&Ps[wave][0];
#pragma unroll
        for (int nn = 0; nn < 4; ++nn) {
          u32 lo = cvtpk_bf16(s[nn][0], s[nn][1]);
          u32 hi = cvtpk_bf16(s[nn][2], s[nn][3]);
          int idx = r16 * 32 + (((2 * nn + (g >> 1)) ^ r7) << 2) + 2 * (g & 1);
          *(uint2*)&pw[idx] = make_uint2(lo, hi);
        }
        const u16* pr = &Ps[wave][0];
        short8 pa0 = *(const short8*)&pr[off0];  // P[q=r16][local keys 8g..8g+7]
        short8 pa1 = *(const short8*)&pr[off1];  // P[q=r16][local keys 32+8g..]

        // ---- O-partial += P V (4 d-tiles x 2 key-32 MFMAs) ----
        __builtin_amdgcn_s_setprio(1);
#pragma unroll
        for (int n = 0; n < 4; ++n) {
          short8 vf0 = *(const short8*)&Vc[n * 2048 + vo0];
          short8 vf1 = *(const short8*)&Vc[n * 2048 + vo1];
          acc[n] = MFMA(pa0, vf0, acc[n]);
          acc[n] = MFMA(pa1, vf1, acc[n]);
        }
        __builtin_amdgcn_s_setprio(0);
      }
      __builtin_amdgcn_sched_barrier(0);
    }

    // ---- strip end: cross-g l combine, pairwise (m,l,O) merge, store ----
    float lt = lrun + __shfl_xor(lrun, 16);
    lt += __shfl_xor(lt, 32);              // full per-q sum (valid in all lanes)

    __syncthreads();  // all waves done with K/V slots (frees Ks for merge buffers)
    float* ab = (float*)&Ks[0][0] + qgrp * 1024;  // [16 q][64 d] f32 per pair (16KB tot)
    if (kh == 1) {
#pragma unroll
      for (int n = 0; n < 4; ++n)
#pragma unroll
        for (int r = 0; r < 4; ++r)
          ab[(4 * g + r) * 64 + 16 * n + r16] = acc[n][r];
      if (g == 0) {
        ml[qgrp * 32 + r16 * 2]     = mrun;
        ml[qgrp * 32 + r16 * 2 + 1] = lt;
      }
    }
    __syncthreads();
    if (kh == 0) {
#pragma unroll
      for (int r = 0; r < 4; ++r) {
        int q = 4 * g + r;
        float mA = __shfl(mrun, q);
        float lA = __shfl(lt, q);
        float mB = ml[qgrp * 32 + q * 2];
        float lB = ml[qgrp * 32 + q * 2 + 1];
        float ms = fmaxf(mA, mB);
        float cA = fexp2(mA - ms);
        float cB = fexp2(mB - ms);
        float linv = 1.0f / (lA * cA + lB * cB);
        int qr = q0 + qgrp * 16 + q;
        u16* orow = O + ((size_t)(b * Tc + qr)) * Hc + h * 64;
#pragma unroll
        for (int n = 0; n < 4; ++n) {
          float v = (acc[n][r] * cA + ab[q * 64 + 16 * n + r16] * cB) * linv;
          orow[n * 16 + r16] = f2bf(v);
        }
      }
    }
    // loop-top __syncthreads orders merge reads before next strip's staging writes
  }
}

// ---------------- launch ----------------
extern "C" void kernel_launch(void* const* d_in, const int* in_sizes, int n_in,
                              void* d_out, int out_size, void* d_ws, size_t ws_size,
                              hipStream_t stream) {
  const float* x = (const float*)d_in[0];
  const int* mask = (const int*)d_in[1];
  const float* Wqkv = (const float*)d_in[2];
  const float* bqkv = (const float*)d_in[3];
  const float* Wproj = (const float*)d_in[4];
  const float* bproj = (const float*)d_in[5];
  float* out = (float*)d_out;

  char* ws = (char*)d_ws;
  size_t off = 0;
  auto alloc = [&](size_t bytes) {
    char* p = ws + off;
    off += (bytes + 255) & ~(size_t)255;
    return p;
  };
  u16* xb     = (u16*)alloc((size_t)BTc * Hc * 2);
  u16* WqkvT  = (u16*)alloc((size_t)N3 * Hc * 2);
  u16* WprojT = (u16*)alloc((size_t)Hc * Hc * 2);
  u16* Qh     = (u16*)alloc((size_t)BTc * Hc * 2);
  u16* Kh     = (u16*)alloc((size_t)BTc * Hc * 2);
  u16* VT     = (u16*)alloc((size_t)BTc * Hc * 2);
  u32* ctr    = (u32*)alloc(256);
  u8*  flags  = (u8*)alloc(256);
  u16* Ob     = xb;  // alias: xb dead after GEMM1, reused for attention output

  int n8 = BTc * Hc / 8;
  k_cvt<<<(n8 + 255) / 256, 256, 0, stream>>>((const float4*)x, (uint4*)xb, n8,
                                              mask, flags, ctr);
  k_transpose_w2<<<dim3(36, 24), dim3(64, 4), 0, stream>>>(Wqkv, Wproj, WqkvT, WprojT);
  k_gemm<0><<<dim3(N3 / 128, BTc / 128), 256, 0, stream>>>(xb, WqkvT, bqkv, Qh, Kh, VT,
                                                           nullptr, BTc, N3, Hc);
  k_attn<<<dim3(512), 512, 0, stream>>>(Qh, Kh, VT, mask, flags, Ob, ctr);
  k_gemm<1><<<dim3(Hc / 128, BTc / 128), 256, 0, stream>>>(Ob, WprojT, bproj, nullptr,
                                                           nullptr, nullptr, out, BTc, Hc, Hc);
}